// Round 5
// baseline (307.259 us; speedup 1.0000x reference)
//
#include <hip/hip_runtime.h>

#define N_NODES 10000
#define E_EDGES 320000
#define HDIM    256
#define NG      20
#define BN_EPS  1e-5f
#define EB      128   // edges per block (E/EB = 2500)
#define RB      32    // node rows per block (ceil(N/RB) = 313)

typedef __attribute__((ext_vector_type(8))) short short8;
typedef __attribute__((ext_vector_type(4))) float f32x4;
typedef __attribute__((ext_vector_type(4))) unsigned int u32x4;

__device__ __forceinline__ float silu_f(float v) {
    float e = __expf(-v);
    return v * __builtin_amdgcn_rcpf(1.0f + e);
}

__device__ __forceinline__ unsigned int cvt_pk(float lo, float hi) {
    unsigned int r;
    asm("v_cvt_pk_bf16_f32 %0, %1, %2" : "=v"(r) : "v"(lo), "v"(hi));
    return r;
}

__device__ __forceinline__ unsigned short f2bf(float f) {
    union { float f; unsigned int u; } v; v.f = f;
    unsigned int r = v.u + 0x7fffu + ((v.u >> 16) & 1u);   // RNE
    return (unsigned short)(r >> 16);
}

__device__ __forceinline__ short8 mk_s8(unsigned int a, unsigned int b,
                                        unsigned int c, unsigned int d) {
    union { u32x4 u; short8 s; } v;
    v.u = (u32x4){a, b, c, d};
    return v.s;
}

// ---------------------------------------------------------------------------
// Fused prep (weight packing -> bf16 MFMA fragment layout) + edge histogram.
// blocks [0,800): pack Pf2/Pu1/Pu2 (3x65536) + P1 (8192)
// blocks [800,2050): histogram of ei_row into cnt
// ---------------------------------------------------------------------------
__global__ __launch_bounds__(256) void prep_hist_kernel(
    const float* __restrict__ Wf2, const float* __restrict__ Wu1,
    const float* __restrict__ Wu2, const float* __restrict__ Wf1,
    const float* __restrict__ bf1, const int* __restrict__ ei_row,
    unsigned short* __restrict__ Pf2, unsigned short* __restrict__ Pu1,
    unsigned short* __restrict__ Pu2, unsigned short* __restrict__ P1,
    int* __restrict__ cnt)
{
    const int bx = blockIdx.x;
    if (bx >= 800) {
        int e = (bx - 800) * 256 + threadIdx.x;
        atomicAdd(&cnt[ei_row[e]], 1);
        return;
    }
    int tid = bx * 256 + threadIdx.x;
    if (tid < 196608) {
        int which = tid >> 16, local = tid & 65535;
        const float* W = (which == 0) ? Wf2 : (which == 1) ? Wu1 : Wu2;
        unsigned short* P = (which == 0) ? Pf2 : (which == 1) ? Pu1 : Pu2;
        int j = local & 7, lane = (local >> 3) & 63;
        int ntile = (local >> 9) & 15, kstep = local >> 13;
        int k = kstep * 32 + (lane >> 4) * 8 + j;
        int n = ntile * 16 + (lane & 15);
        P[local] = f2bf(W[k * 256 + n]);
    } else {
        int local = tid - 196608;   // 0..8191
        int j = local & 7, lane = (local >> 3) & 63, ntile = local >> 9;
        int k = (lane >> 4) * 8 + j;
        int n = ntile * 16 + (lane & 15);
        float v = (k < NG) ? Wf1[k * 256 + n] : (k == NG ? bf1[n] : 0.0f);
        P1[local] = f2bf(v);
    }
}

// ---------------------------------------------------------------------------
// CSR build: scan + fill
// ---------------------------------------------------------------------------
__global__ __launch_bounds__(256) void scan_kernel(int* __restrict__ cnt) {
    __shared__ int tot[256];
    const int t = threadIdx.x;
    int loc[40];
    int s = 0;
    #pragma unroll
    for (int i = 0; i < 40; ++i) { loc[i] = cnt[t * 40 + i]; s += loc[i]; }
    tot[t] = s;
    __syncthreads();
    for (int off = 1; off < 256; off <<= 1) {
        int u = (t >= off) ? tot[t - off] : 0;
        __syncthreads();
        tot[t] += u;
        __syncthreads();
    }
    int pre = tot[t] - s;
    #pragma unroll
    for (int i = 0; i < 40; ++i) { int v = loc[i]; cnt[t * 40 + i] = pre; pre += v; }
}

__global__ __launch_bounds__(256) void fill_kernel(const int* __restrict__ ei_row,
                                                   int* __restrict__ cnt,
                                                   int* __restrict__ perm,
                                                   int* __restrict__ nodepos) {
    int e = blockIdx.x * 256 + threadIdx.x;
    int r = ei_row[e];
    int pos = atomicAdd(&cnt[r], 1);
    perm[pos] = e;
    nodepos[pos] = r;
}

// ---------------------------------------------------------------------------
// Edge kernel: 128 CSR-ordered edges / block, 512 threads (8 waves),
// LDS = exactly 64KB (hid buffer, msg overlays it).
// Wave w: wq=w&3 -> cols wq*64..+63 (4 mt tiles); wh=w>>2 -> edges wh*64..+63
// (4 nt tiles).
// GEMM1: hiddenT = Wf1T.rbfT, B-frags gathered per-lane from global rbf
//        (bias row = 1.0 constant), silu -> hid LDS (bf16, XOR swizzle).
// GEMM2: filtT = Wf2T.hiddenT, A-frags streamed from L2-resident packed W.
// msg:   (filt+bf2)*x[col] -> f32 overlay (2 passes x 64 rows), 512-thread
//        segmented column reduce, few atomics into agg.
// ---------------------------------------------------------------------------
__global__ __launch_bounds__(512, 4) void edge_kernel(
    const float* __restrict__ rbf, const int* __restrict__ ei_col,
    const int* __restrict__ perm, const int* __restrict__ nodepos,
    const unsigned short* __restrict__ P1, const unsigned short* __restrict__ P2,
    const float* __restrict__ bf2, const float* __restrict__ x,
    float* __restrict__ agg)
{
    __shared__ char sm[65536];

    const int t = threadIdx.x;
    int blk = blockIdx.x;
    {   // bijective XCD swizzle: nwg=2500, q=312, r=4
        int xcd = blk & 7, i = blk >> 3;
        blk = (xcd < 4 ? xcd * 313 : 1252 + (xcd - 4) * 312) + i;
    }
    const int p0 = blk * EB;
    const int l = t & 63, w = t >> 6;
    const int wq = w & 3, wh = w >> 2;
    const int l15 = l & 15, l4 = l >> 4;

    // per-thread edge metadata (4 rows of this wave's edge half)
    int rowsl[4], ecol[4];
    const float* rbfp[4];
    #pragma unroll
    for (int nt = 0; nt < 4; ++nt) {
        int row = wh * 64 + nt * 16 + l15;
        rowsl[nt] = row;
        int e = perm[p0 + row];
        ecol[nt] = ei_col[e];
        rbfp[nt] = rbf + (size_t)e * NG;
    }

    // GEMM1 A-frags (Wf1T, K=32 incl. bias row)
    short8 a1[4];
    #pragma unroll
    for (int mt = 0; mt < 4; ++mt)
        a1[mt] = *(const short8*)(P1 + ((4 * wq + mt) * 64 + l) * 8);

    f32x4 acc[4][4];   // [mt][nt]
    #pragma unroll
    for (int mt = 0; mt < 4; ++mt)
        #pragma unroll
        for (int nt = 0; nt < 4; ++nt) acc[mt][nt] = (f32x4)0.0f;

    // GEMM1: B-frags gathered from global rbf (lane l4 owns k = l4*8..l4*8+7)
    #pragma unroll
    for (int nt = 0; nt < 4; ++nt) {
        short8 bfr;
        if (l4 < 2) {
            float4 fa = *(const float4*)(rbfp[nt] + l4 * 8);
            float4 fb = *(const float4*)(rbfp[nt] + l4 * 8 + 4);
            bfr = mk_s8(cvt_pk(fa.x, fa.y), cvt_pk(fa.z, fa.w),
                        cvt_pk(fb.x, fb.y), cvt_pk(fb.z, fb.w));
        } else if (l4 == 2) {
            float4 fa = *(const float4*)(rbfp[nt] + 16);
            bfr = mk_s8(cvt_pk(fa.x, fa.y), cvt_pk(fa.z, fa.w),
                        0x00003f80u /*k=20 bias row = 1.0*/, 0u);
        } else {
            bfr = mk_s8(0u, 0u, 0u, 0u);
        }
        #pragma unroll
        for (int mt = 0; mt < 4; ++mt)
            acc[mt][nt] = __builtin_amdgcn_mfma_f32_16x16x32_bf16(a1[mt], bfr, acc[mt][nt], 0, 0, 0);
    }

    // silu -> hid[row][col] bf16, XOR-swizzled, b64 stores
    #pragma unroll
    for (int mt = 0; mt < 4; ++mt) {
        const int hc0 = wq * 64 + mt * 16 + l4 * 4;
        #pragma unroll
        for (int nt = 0; nt < 4; ++nt) {
            const int row = rowsl[nt];
            unsigned int pk0 = cvt_pk(silu_f(acc[mt][nt][0]), silu_f(acc[mt][nt][1]));
            unsigned int pk1 = cvt_pk(silu_f(acc[mt][nt][2]), silu_f(acc[mt][nt][3]));
            *(uint2*)(sm + row * 512 + (((hc0 >> 3) ^ (row & 7)) << 4) + (hc0 & 7) * 2) =
                make_uint2(pk0, pk1);
        }
    }

    // GEMM2 ks=0 A-frags (issue loads before the barrier)
    short8 acur[4];
    #pragma unroll
    for (int mt = 0; mt < 4; ++mt)
        acur[mt] = *(const short8*)(P2 + ((4 * wq + mt) * 64 + l) * 8);

    __syncthreads();   // hid complete

    #pragma unroll
    for (int mt = 0; mt < 4; ++mt)
        #pragma unroll
        for (int nt = 0; nt < 4; ++nt) acc[mt][nt] = (f32x4)0.0f;

    for (int ks = 0; ks < 8; ++ks) {
        short8 anext[4];
        if (ks < 7) {
            #pragma unroll
            for (int mt = 0; mt < 4; ++mt)
                anext[mt] = *(const short8*)(P2 + (((ks + 1) * 16 + 4 * wq + mt) * 64 + l) * 8);
        }
        #pragma unroll
        for (int nt = 0; nt < 4; ++nt) {
            const int row = rowsl[nt];
            short8 bfh = *(const short8*)(sm + row * 512 +
                            ((((ks << 2) + l4) ^ (row & 7)) << 4));
            #pragma unroll
            for (int mt = 0; mt < 4; ++mt)
                acc[mt][nt] = __builtin_amdgcn_mfma_f32_16x16x32_bf16(acur[mt], bfh, acc[mt][nt], 0, 0, 0);
        }
        if (ks < 7) {
            #pragma unroll
            for (int mt = 0; mt < 4; ++mt) acur[mt] = anext[mt];
        }
    }
    __syncthreads();   // all hid reads done -> msg overlay

    f32x4 bc4[4];
    #pragma unroll
    for (int mt = 0; mt < 4; ++mt)
        bc4[mt] = *(const f32x4*)(bf2 + wq * 64 + mt * 16 + l4 * 4);

    const int rcol = t & 255;      // reduce column
    const int rh   = t >> 8;       // reduce row-chunk (0/1)

    #pragma unroll
    for (int ps = 0; ps < 2; ++ps) {
        // write pass: waves with wh==ps store their 64 edge rows (local 0..63)
        if (wh == ps) {
            #pragma unroll
            for (int nt = 0; nt < 4; ++nt) {
                const int lrow = nt * 16 + l15;
                const float* xp = x + (size_t)ecol[nt] * HDIM;
                #pragma unroll
                for (int mt = 0; mt < 4; ++mt) {
                    const int fc0 = wq * 64 + mt * 16 + l4 * 4;
                    f32x4 xv = *(const f32x4*)(xp + fc0);
                    f32x4 mv = (acc[mt][nt] + bc4[mt]) * xv;
                    *(f32x4*)(sm + lrow * 1024 + (((fc0 >> 2) ^ (lrow & 7)) << 4)) = mv;
                }
            }
        }
        __syncthreads();
        // reduce pass: 512 threads = 256 cols x 2 row-chunks of 32
        {
            const int base = p0 + ps * 64 + rh * 32;
            float sum = 0.0f;
            int cur = nodepos[base];
            #pragma unroll 8
            for (int pos = 0; pos < 32; ++pos) {
                const int lrow = rh * 32 + pos;
                const int nid = nodepos[base + pos];
                float v = *(const float*)(sm + lrow * 1024 +
                            (((rcol >> 2) ^ (lrow & 7)) << 4) + (rcol & 3) * 4);
                if (nid != cur) {
                    atomicAdd(&agg[(size_t)cur * HDIM + rcol], sum);
                    sum = 0.0f; cur = nid;
                }
                sum += v;
            }
            atomicAdd(&agg[(size_t)cur * HDIM + rcol], sum);
        }
        __syncthreads();
    }
}

// ---------------------------------------------------------------------------
// Node kernel: 32 rows/block (313 blocks). Both GEMMs swapped; fused BN
// partials. LDS 16KB.
// ---------------------------------------------------------------------------
__global__ __launch_bounds__(256, 4) void node_kernel(
    const float* __restrict__ agg, const float* __restrict__ bu1,
    const float* __restrict__ bu2,
    const unsigned short* __restrict__ Pu1, const unsigned short* __restrict__ Pu2,
    float* __restrict__ hout, float* __restrict__ sums)
{
    __shared__ char sm[16384];   // [32 rows][512B] bf16, XOR-swizzled
    const int t  = threadIdx.x;
    const int r0 = blockIdx.x * RB;
    const int l = t & 63, w = t >> 6;
    const int l15 = l & 15, l4 = l >> 4;

    // stage agg -> LDS bf16
    {
        const int row = t & 31, q = t >> 5;
        const bool valid = (r0 + row) < N_NODES;
        const float4* src = (const float4*)(agg + (size_t)(r0 + row) * HDIM) + q * 8;
        #pragma unroll
        for (int i = 0; i < 8; ++i) {
            float4 v = valid ? src[i] : make_float4(0.f, 0.f, 0.f, 0.f);
            const int c0 = q * 32 + i * 4;
            *(uint2*)(sm + row * 512 + (((c0 >> 3) ^ (row & 7)) << 4) + (c0 & 7) * 2) =
                make_uint2(cvt_pk(v.x, v.y), cvt_pk(v.z, v.w));
        }
    }

    short8 acur[4];
    #pragma unroll
    for (int mt = 0; mt < 4; ++mt)
        acur[mt] = *(const short8*)(Pu1 + ((4 * w + mt) * 64 + l) * 8);

    __syncthreads();

    f32x4 acc[4][2];
    #pragma unroll
    for (int mt = 0; mt < 4; ++mt)
        #pragma unroll
        for (int nt = 0; nt < 2; ++nt) acc[mt][nt] = (f32x4)0.0f;

    // GEMM1': midT = Wu1T.aggT
    for (int ks = 0; ks < 8; ++ks) {
        short8 anext[4];
        if (ks < 7) {
            #pragma unroll
            for (int mt = 0; mt < 4; ++mt)
                anext[mt] = *(const short8*)(Pu1 + (((ks + 1) * 16 + 4 * w + mt) * 64 + l) * 8);
        }
        #pragma unroll
        for (int nt = 0; nt < 2; ++nt) {
            const int row = nt * 16 + l15;
            short8 bfa = *(const short8*)(sm + row * 512 +
                            ((((ks << 2) + l4) ^ (row & 7)) << 4));
            #pragma unroll
            for (int mt = 0; mt < 4; ++mt)
                acc[mt][nt] = __builtin_amdgcn_mfma_f32_16x16x32_bf16(acur[mt], bfa, acc[mt][nt], 0, 0, 0);
        }
        if (ks < 7) {
            #pragma unroll
            for (int mt = 0; mt < 4; ++mt) acur[mt] = anext[mt];
        }
    }
    __syncthreads();   // all reads done

    #pragma unroll
    for (int mt = 0; mt < 4; ++mt)
        acur[mt] = *(const short8*)(Pu2 + ((4 * w + mt) * 64 + l) * 8);

    // mid = silu(acc + bu1) -> LDS
    #pragma unroll
    for (int mt = 0; mt < 4; ++mt) {
        const int mc0 = w * 64 + mt * 16 + l4 * 4;
        f32x4 b4 = *(const f32x4*)(bu1 + mc0);
        #pragma unroll
        for (int nt = 0; nt < 2; ++nt) {
            const int row = nt * 16 + l15;
            unsigned int pk0 = cvt_pk(silu_f(acc[mt][nt][0] + b4[0]), silu_f(acc[mt][nt][1] + b4[1]));
            unsigned int pk1 = cvt_pk(silu_f(acc[mt][nt][2] + b4[2]), silu_f(acc[mt][nt][3] + b4[3]));
            *(uint2*)(sm + row * 512 + (((mc0 >> 3) ^ (row & 7)) << 4) + (mc0 & 7) * 2) =
                make_uint2(pk0, pk1);
            acc[mt][nt] = (f32x4)0.0f;
        }
    }
    __syncthreads();

    // GEMM2': hT = Wu2T.midT
    for (int ks = 0; ks < 8; ++ks) {
        short8 anext[4];
        if (ks < 7) {
            #pragma unroll
            for (int mt = 0; mt < 4; ++mt)
                anext[mt] = *(const short8*)(Pu2 + (((ks + 1) * 16 + 4 * w + mt) * 64 + l) * 8);
        }
        #pragma unroll
        for (int nt = 0; nt < 2; ++nt) {
            const int row = nt * 16 + l15;
            short8 bfm = *(const short8*)(sm + row * 512 +
                            ((((ks << 2) + l4) ^ (row & 7)) << 4));
            #pragma unroll
            for (int mt = 0; mt < 4; ++mt)
                acc[mt][nt] = __builtin_amdgcn_mfma_f32_16x16x32_bf16(acur[mt], bfm, acc[mt][nt], 0, 0, 0);
        }
        if (ks < 7) {
            #pragma unroll
            for (int mt = 0; mt < 4; ++mt) acur[mt] = anext[mt];
        }
    }

    // epilogue: float4 h stores + BN partials
    #pragma unroll
    for (int mt = 0; mt < 4; ++mt) {
        const int hc0 = w * 64 + mt * 16 + l4 * 4;
        f32x4 b4 = *(const f32x4*)(bu2 + hc0);
        f32x4 s = (f32x4)0.0f, s2 = (f32x4)0.0f;
        #pragma unroll
        for (int nt = 0; nt < 2; ++nt) {
            const int gr = r0 + nt * 16 + l15;
            if (gr < N_NODES) {
                f32x4 hv = acc[mt][nt] + b4;
                *(f32x4*)(hout + (size_t)gr * HDIM + hc0) = hv;
                s += hv; s2 += hv * hv;
            }
        }
        #pragma unroll
        for (int off = 1; off < 16; off <<= 1) {
            #pragma unroll
            for (int r = 0; r < 4; ++r) {
                s[r]  += __shfl_xor(s[r], off);
                s2[r] += __shfl_xor(s2[r], off);
            }
        }
        if (l15 == 0) {
            #pragma unroll
            for (int r = 0; r < 4; ++r) {
                atomicAdd(&sums[hc0 + r], s[r]);
                atomicAdd(&sums[HDIM + hc0 + r], s2[r]);
            }
        }
    }
}

// ---------------------------------------------------------------------------
__global__ __launch_bounds__(256) void final_kernel(
    const float* __restrict__ x, const float* __restrict__ sums,
    const float* __restrict__ gamma, const float* __restrict__ beta,
    float* __restrict__ out)
{
    const int i4 = blockIdx.x * 256 + threadIdx.x;   // float4 index
    const int j  = (i4 & 63) * 4;
    f32x4 mean = *(const f32x4*)(sums + j) * (1.0f / N_NODES);
    f32x4 s2   = *(const f32x4*)(sums + HDIM + j) * (1.0f / N_NODES);
    f32x4 g    = *(const f32x4*)(gamma + j);
    f32x4 b    = *(const f32x4*)(beta + j);
    f32x4 hv   = ((f32x4*)out)[i4];
    f32x4 xv   = ((const f32x4*)x)[i4];
    f32x4 var  = s2 - mean * mean;
    f32x4 inv;
    #pragma unroll
    for (int r = 0; r < 4; ++r) inv[r] = rsqrtf(var[r] + BN_EPS);
    ((f32x4*)out)[i4] = xv + g * (hv - mean) * inv + b;
}

extern "C" void kernel_launch(void* const* d_in, const int* in_sizes, int n_in,
                              void* d_out, int out_size, void* d_ws, size_t ws_size,
                              hipStream_t stream) {
    const float* x     = (const float*)d_in[0];
    const float* rbf   = (const float*)d_in[1];
    const int*   ei    = (const int*)d_in[2];
    const float* Wf1   = (const float*)d_in[3];
    const float* bf1   = (const float*)d_in[4];
    const float* Wf2   = (const float*)d_in[5];
    const float* bf2   = (const float*)d_in[6];
    const float* Wu1   = (const float*)d_in[7];
    const float* bu1   = (const float*)d_in[8];
    const float* Wu2   = (const float*)d_in[9];
    const float* bu2   = (const float*)d_in[10];
    const float* gamma = (const float*)d_in[11];
    const float* beta  = (const float*)d_in[12];
    float* out = (float*)d_out;

    char* ws = (char*)d_ws;
    float* agg     = (float*)(ws);                            // 10,240,000 B
    float* sums    = (float*)(ws + 10240000);                 // 2,048 B
    int*   cnt     = (int*)(ws + 10242048);                   // 40,960 B
    int*   perm    = (int*)(ws + 10283008);                   // 1,280,000 B
    int*   nodepos = (int*)(ws + 11563008);                   // 1,280,000 B
    unsigned short* Pf2 = (unsigned short*)(ws + 12843008);   // 131,072 B
    unsigned short* Pu1 = (unsigned short*)(ws + 12974080);   // 131,072 B
    unsigned short* Pu2 = (unsigned short*)(ws + 13105152);   // 131,072 B
    unsigned short* P1  = (unsigned short*)(ws + 13236224);   // 16,384 B

    // one memset covers agg + sums + cnt (contiguous)
    hipMemsetAsync(agg, 0, 10283008, stream);

    prep_hist_kernel<<<2050, 256, 0, stream>>>(Wf2, Wu1, Wu2, Wf1, bf1, ei,
                                               Pf2, Pu1, Pu2, P1, cnt);
    scan_kernel<<<1, 256, 0, stream>>>(cnt);
    fill_kernel<<<E_EDGES / 256, 256, 0, stream>>>(ei, cnt, perm, nodepos);

    edge_kernel<<<E_EDGES / EB, 512, 0, stream>>>(
        rbf, ei + E_EDGES, perm, nodepos, P1, Pf2, bf2, x, agg);
    node_kernel<<<(N_NODES + RB - 1) / RB, 256, 0, stream>>>(
        agg, bu1, bu2, Pu1, Pu2, out, sums);
    final_kernel<<<(N_NODES * HDIM / 4) / 256, 256, 0, stream>>>(
        x, sums, gamma, beta, out);
}

// Round 6
// 244.123 us; speedup vs baseline: 1.2586x; 1.2586x over previous
//
#include <hip/hip_runtime.h>

#define N_NODES 10000
#define E_EDGES 320000
#define HDIM    256
#define NG      20
#define BN_EPS  1e-5f
#define RB      16    // node rows per block (10000/16 = 625 exact)

typedef __attribute__((ext_vector_type(8))) short short8;
typedef __attribute__((ext_vector_type(4))) float f32x4;

__device__ __forceinline__ float silu_f(float v) {
    float e = __expf(-v);
    return v * __builtin_amdgcn_rcpf(1.0f + e);
}

__device__ __forceinline__ unsigned int cvt_pk(float lo, float hi) {
    unsigned int r;
    asm("v_cvt_pk_bf16_f32 %0, %1, %2" : "=v"(r) : "v"(lo), "v"(hi));
    return r;
}

__device__ __forceinline__ unsigned short f2bf(float f) {
    union { float f; unsigned int u; } v; v.f = f;
    unsigned int r = v.u + 0x7fffu + ((v.u >> 16) & 1u);   // RNE
    return (unsigned short)(r >> 16);
}

// ---------------------------------------------------------------------------
// Fused prep (weight packing -> bf16 MFMA fragment layout) + edge histogram.
// blocks [0,800): pack Pf2/Pu1/Pu2 (3x65536) + P1 (8192)
// blocks [800,2050): histogram of ei_row into cnt
// ---------------------------------------------------------------------------
__global__ __launch_bounds__(256) void prep_hist_kernel(
    const float* __restrict__ Wf2, const float* __restrict__ Wu1,
    const float* __restrict__ Wu2, const float* __restrict__ Wf1,
    const float* __restrict__ bf1, const int* __restrict__ ei_row,
    unsigned short* __restrict__ Pf2, unsigned short* __restrict__ Pu1,
    unsigned short* __restrict__ Pu2, unsigned short* __restrict__ P1,
    int* __restrict__ cnt)
{
    const int bx = blockIdx.x;
    if (bx >= 800) {
        int e = (bx - 800) * 256 + threadIdx.x;
        atomicAdd(&cnt[ei_row[e]], 1);
        return;
    }
    int tid = bx * 256 + threadIdx.x;
    if (tid < 196608) {
        int which = tid >> 16, local = tid & 65535;
        const float* W = (which == 0) ? Wf2 : (which == 1) ? Wu1 : Wu2;
        unsigned short* P = (which == 0) ? Pf2 : (which == 1) ? Pu1 : Pu2;
        int j = local & 7, lane = (local >> 3) & 63;
        int ntile = (local >> 9) & 15, kstep = local >> 13;
        int k = kstep * 32 + (lane >> 4) * 8 + j;
        int n = ntile * 16 + (lane & 15);
        P[local] = f2bf(W[k * 256 + n]);
    } else {
        int local = tid - 196608;   // 0..8191
        int j = local & 7, lane = (local >> 3) & 63, ntile = local >> 9;
        int k = (lane >> 4) * 8 + j;
        int n = ntile * 16 + (lane & 15);
        float v = (k < NG) ? Wf1[k * 256 + n] : (k == NG ? bf1[n] : 0.0f);
        P1[local] = f2bf(v);
    }
}

// ---------------------------------------------------------------------------
// CSR build: scan + fill
// ---------------------------------------------------------------------------
__global__ __launch_bounds__(256) void scan_kernel(int* __restrict__ cnt) {
    __shared__ int tot[256];
    const int t = threadIdx.x;
    int loc[40];
    int s = 0;
    #pragma unroll
    for (int i = 0; i < 40; ++i) { loc[i] = cnt[t * 40 + i]; s += loc[i]; }
    tot[t] = s;
    __syncthreads();
    for (int off = 1; off < 256; off <<= 1) {
        int u = (t >= off) ? tot[t - off] : 0;
        __syncthreads();
        tot[t] += u;
        __syncthreads();
    }
    int pre = tot[t] - s;
    #pragma unroll
    for (int i = 0; i < 40; ++i) { int v = loc[i]; cnt[t * 40 + i] = pre; pre += v; }
}

__global__ __launch_bounds__(256) void fill_kernel(const int* __restrict__ ei_row,
                                                   int* __restrict__ cnt,
                                                   int* __restrict__ perm,
                                                   int* __restrict__ nodepos) {
    int e = blockIdx.x * 256 + threadIdx.x;
    int r = ei_row[e];
    int pos = atomicAdd(&cnt[r], 1);
    perm[pos] = e;
    nodepos[pos] = r;
}

// ---------------------------------------------------------------------------
// Edge kernel: 64 CSR-ordered edges / block, 4 waves (round-4 structure).
// GEMM1 (swapped): hiddenT = Wf1T.rbfT; rbf staged ONCE in LDS (stride 80B,
//   conflict-free); silu + cvt_pk -> hid LDS (bf16, XOR swizzle).
// GEMM2 (swapped): filtT = Wf2T.hiddenT; A-frags streamed from L2 packed W;
//   x gathers for edge rows 0..31 prefetched at ks==6 (hidden under MFMA).
// msg: (filt+bf2)*x[col] -> f32 overlay; x for rows 32..63 issued before the
//   first reduce pass (hidden under it); serial segmented column reduce.
// ---------------------------------------------------------------------------
#define SM_NID 0        // 64 int
#define SM_COL 256      // 64 int
#define SM_RBF 512      // [64][40] ushort rows of 80 B (5120 B)
#define SM_HID 5632     // 32768 B: hid bf16 [64][256] swz / msg f32 [32][256] swz
#define SM_TOT 38400

__global__ __launch_bounds__(256, 3) void edge_kernel(
    const float* __restrict__ rbf, const int* __restrict__ ei_col,
    const int* __restrict__ perm, const int* __restrict__ nodepos,
    const unsigned short* __restrict__ P1, const unsigned short* __restrict__ P2,
    const float* __restrict__ bf2, const float* __restrict__ x,
    float* __restrict__ agg)
{
    __shared__ char sm[SM_TOT];
    int* nid_s = (int*)(sm + SM_NID);
    int* col_s = (int*)(sm + SM_COL);

    const int t = threadIdx.x;
    int blk = blockIdx.x;
    blk = (blk & 7) * 625 + (blk >> 3);   // XCD swizzle (5000 = 8*625, bijective)
    const int p0 = blk * 64;
    const int l = t & 63, w = t >> 6;
    const int l15 = l & 15, l4 = l >> 4;

    if (t < 64) {
        nid_s[t] = nodepos[p0 + t];
        col_s[t] = ei_col[perm[p0 + t]];
    }
    // rbf -> LDS bf16, 80 B rows; k=20 bias row (1.0), 21..31 zero
    if (t < 128) {
        const int row = t >> 1, half = t & 1;
        const float* rp = rbf + (size_t)perm[p0 + row] * NG + half * 10;
        float v[10];
        if (half == 0) {
            float4 a = *(const float4*)rp, b = *(const float4*)(rp + 4);
            float2 c = *(const float2*)(rp + 8);
            v[0]=a.x; v[1]=a.y; v[2]=a.z; v[3]=a.w; v[4]=b.x;
            v[5]=b.y; v[6]=b.z; v[7]=b.w; v[8]=c.x; v[9]=c.y;
        } else {
            float2 a = *(const float2*)rp;
            float4 b = *(const float4*)(rp + 2), c = *(const float4*)(rp + 6);
            v[0]=a.x; v[1]=a.y; v[2]=b.x; v[3]=b.y; v[4]=b.z;
            v[5]=b.w; v[6]=c.x; v[7]=c.y; v[8]=c.z; v[9]=c.w;
        }
        unsigned int* dst = (unsigned int*)(sm + SM_RBF + row * 80 + half * 20);
        #pragma unroll
        for (int i = 0; i < 5; ++i) dst[i] = cvt_pk(v[2*i], v[2*i+1]);
    } else if (t < 192) {
        const int row = t - 128;
        *(unsigned long long*)(sm + SM_RBF + row * 80 + 40) = 0x3F80ull; // 1.0,0,0,0
        *(uint4*)(sm + SM_RBF + row * 80 + 48) = make_uint4(0, 0, 0, 0);
    }

    // GEMM1 A-frags (Wf1T) and GEMM2 ks=0 A-frags (Wf2T) from global
    short8 a1[4], acur[4];
    #pragma unroll
    for (int mt = 0; mt < 4; ++mt) {
        a1[mt]   = *(const short8*)(P1 + ((4 * w + mt) * 64 + l) * 8);
        acur[mt] = *(const short8*)(P2 + ((4 * w + mt) * 64 + l) * 8);
    }

    __syncthreads();

    const float* xbase[4];
    #pragma unroll
    for (int nt = 0; nt < 4; ++nt)
        xbase[nt] = x + (size_t)col_s[nt * 16 + l15] * HDIM;

    f32x4 acc[4][4];   // [mt][nt]
    #pragma unroll
    for (int mt = 0; mt < 4; ++mt)
        #pragma unroll
        for (int nt = 0; nt < 4; ++nt) acc[mt][nt] = (f32x4)0.0f;

    // GEMM1: one K=32 step; B = rbfT from LDS (stride 80B)
    #pragma unroll
    for (int nt = 0; nt < 4; ++nt) {
        short8 bfr = *(const short8*)(sm + SM_RBF + (nt * 16 + l15) * 80 + l4 * 16);
        #pragma unroll
        for (int mt = 0; mt < 4; ++mt)
            acc[mt][nt] = __builtin_amdgcn_mfma_f32_16x16x32_bf16(a1[mt], bfr, acc[mt][nt], 0, 0, 0);
    }

    // silu -> hid bf16, XOR-swizzled, b64 stores (4 consecutive cols/thread)
    #pragma unroll
    for (int mt = 0; mt < 4; ++mt) {
        const int hc0 = w * 64 + mt * 16 + l4 * 4;
        #pragma unroll
        for (int nt = 0; nt < 4; ++nt) {
            const int row = nt * 16 + l15;
            unsigned int pk0 = cvt_pk(silu_f(acc[mt][nt][0]), silu_f(acc[mt][nt][1]));
            unsigned int pk1 = cvt_pk(silu_f(acc[mt][nt][2]), silu_f(acc[mt][nt][3]));
            *(uint2*)(sm + SM_HID + row * 512 +
                      (((hc0 >> 3) ^ (row & 7)) << 4) + (hc0 & 7) * 2) =
                make_uint2(pk0, pk1);
        }
    }
    __syncthreads();

    // GEMM2: filtT = Wf2T.hiddenT; x prefetch for edge rows 0..31 at ks==6
    #pragma unroll
    for (int mt = 0; mt < 4; ++mt)
        #pragma unroll
        for (int nt = 0; nt < 4; ++nt) acc[mt][nt] = (f32x4)0.0f;

    f32x4 xp[8];   // [nt-within-pass][mt]: xp[mt] for nt-even, xp[4+mt] for nt-odd

    for (int ks = 0; ks < 8; ++ks) {
        short8 anext[4];
        if (ks < 7) {
            #pragma unroll
            for (int mt = 0; mt < 4; ++mt)
                anext[mt] = *(const short8*)(P2 + (((ks + 1) * 16 + 4 * w + mt) * 64 + l) * 8);
        }
        if (ks == 6) {
            #pragma unroll
            for (int mt = 0; mt < 4; ++mt) {
                const int fc0 = w * 64 + mt * 16 + l4 * 4;
                xp[mt]     = *(const f32x4*)(xbase[0] + fc0);
                xp[4 + mt] = *(const f32x4*)(xbase[1] + fc0);
            }
        }
        #pragma unroll
        for (int nt = 0; nt < 4; ++nt) {
            const int row = nt * 16 + l15;
            short8 bfh = *(const short8*)(sm + SM_HID + row * 512 +
                            ((((ks << 2) + l4) ^ (row & 7)) << 4));
            #pragma unroll
            for (int mt = 0; mt < 4; ++mt)
                acc[mt][nt] = __builtin_amdgcn_mfma_f32_16x16x32_bf16(acur[mt], bfh, acc[mt][nt], 0, 0, 0);
        }
        if (ks < 7) {
            #pragma unroll
            for (int mt = 0; mt < 4; ++mt) acur[mt] = anext[mt];
        }
    }
    __syncthreads();   // all hid reads done -> msg overlay

    f32x4 bc4[4];
    #pragma unroll
    for (int mt = 0; mt < 4; ++mt)
        bc4[mt] = *(const f32x4*)(bf2 + w * 64 + mt * 16 + l4 * 4);

    float sum = 0.0f;
    int cur = nid_s[0];

    // ---- pass 0: edge rows 0..31 ----
    #pragma unroll
    for (int ni = 0; ni < 2; ++ni) {
        const int nt  = ni;
        const int pos = ni * 16 + l15;
        #pragma unroll
        for (int mt = 0; mt < 4; ++mt) {
            const int fc0 = w * 64 + mt * 16 + l4 * 4;
            f32x4 mv = (acc[mt][nt] + bc4[mt]) * xp[ni * 4 + mt];
            *(f32x4*)(sm + SM_HID + pos * 1024 + (((fc0 >> 2) ^ (pos & 7)) << 4)) = mv;
        }
    }
    // issue x loads for edge rows 32..63 (latency hidden under reduce pass 0)
    #pragma unroll
    for (int mt = 0; mt < 4; ++mt) {
        const int fc0 = w * 64 + mt * 16 + l4 * 4;
        xp[mt]     = *(const f32x4*)(xbase[2] + fc0);
        xp[4 + mt] = *(const f32x4*)(xbase[3] + fc0);
    }
    __syncthreads();
    for (int pos = 0; pos < 32; ++pos) {
        const int nid = nid_s[pos];
        float v = *(const float*)(sm + SM_HID + pos * 1024 +
                    (((t >> 2) ^ (pos & 7)) << 4) + (t & 3) * 4);
        if (nid != cur) {
            atomicAdd(&agg[(size_t)cur * HDIM + t], sum);
            sum = 0.0f; cur = nid;
        }
        sum += v;
    }
    __syncthreads();

    // ---- pass 1: edge rows 32..63 ----
    #pragma unroll
    for (int ni = 0; ni < 2; ++ni) {
        const int nt  = 2 + ni;
        const int pos = ni * 16 + l15;
        #pragma unroll
        for (int mt = 0; mt < 4; ++mt) {
            const int fc0 = w * 64 + mt * 16 + l4 * 4;
            f32x4 mv = (acc[mt][nt] + bc4[mt]) * xp[ni * 4 + mt];
            *(f32x4*)(sm + SM_HID + pos * 1024 + (((fc0 >> 2) ^ (pos & 7)) << 4)) = mv;
        }
    }
    __syncthreads();
    for (int pos = 0; pos < 32; ++pos) {
        const int nid = nid_s[32 + pos];
        float v = *(const float*)(sm + SM_HID + pos * 1024 +
                    (((t >> 2) ^ (pos & 7)) << 4) + (t & 3) * 4);
        if (nid != cur) {
            atomicAdd(&agg[(size_t)cur * HDIM + t], sum);
            sum = 0.0f; cur = nid;
        }
        sum += v;
    }
    atomicAdd(&agg[(size_t)cur * HDIM + t], sum);
}

// ---------------------------------------------------------------------------
// Node kernel: 16 rows/block (625 blocks, exact). Both GEMMs swapped; fused
// BN partials. LDS 8KB.
// ---------------------------------------------------------------------------
__global__ __launch_bounds__(256, 4) void node_kernel(
    const float* __restrict__ agg, const float* __restrict__ bu1,
    const float* __restrict__ bu2,
    const unsigned short* __restrict__ Pu1, const unsigned short* __restrict__ Pu2,
    float* __restrict__ hout, float* __restrict__ sums)
{
    __shared__ char sm[8192];   // [16 rows][512B] bf16, XOR-swizzled
    const int t  = threadIdx.x;
    const int r0 = blockIdx.x * RB;
    const int l = t & 63, w = t >> 6;
    const int l15 = l & 15, l4 = l >> 4;

    // stage agg -> LDS bf16 (16 threads/row, 4 float4 each)
    {
        const int row = t & 15, q = t >> 4;
        const float4* src = (const float4*)(agg + (size_t)(r0 + row) * HDIM) + q * 4;
        #pragma unroll
        for (int i = 0; i < 4; ++i) {
            float4 v = src[i];
            const int c0 = q * 16 + i * 4;
            *(uint2*)(sm + row * 512 + (((c0 >> 3) ^ (row & 7)) << 4) + (c0 & 7) * 2) =
                make_uint2(cvt_pk(v.x, v.y), cvt_pk(v.z, v.w));
        }
    }

    short8 acur[4];
    #pragma unroll
    for (int mt = 0; mt < 4; ++mt)
        acur[mt] = *(const short8*)(Pu1 + ((4 * w + mt) * 64 + l) * 8);

    __syncthreads();

    f32x4 acc[4];
    #pragma unroll
    for (int mt = 0; mt < 4; ++mt) acc[mt] = (f32x4)0.0f;

    // GEMM1': midT = Wu1T.aggT
    for (int ks = 0; ks < 8; ++ks) {
        short8 anext[4];
        if (ks < 7) {
            #pragma unroll
            for (int mt = 0; mt < 4; ++mt)
                anext[mt] = *(const short8*)(Pu1 + (((ks + 1) * 16 + 4 * w + mt) * 64 + l) * 8);
        }
        short8 bfa = *(const short8*)(sm + l15 * 512 +
                        ((((ks << 2) + l4) ^ (l15 & 7)) << 4));
        #pragma unroll
        for (int mt = 0; mt < 4; ++mt)
            acc[mt] = __builtin_amdgcn_mfma_f32_16x16x32_bf16(acur[mt], bfa, acc[mt], 0, 0, 0);
        if (ks < 7) {
            #pragma unroll
            for (int mt = 0; mt < 4; ++mt) acur[mt] = anext[mt];
        }
    }
    __syncthreads();   // all reads done

    #pragma unroll
    for (int mt = 0; mt < 4; ++mt)
        acur[mt] = *(const short8*)(Pu2 + ((4 * w + mt) * 64 + l) * 8);

    // mid = silu(acc + bu1) -> LDS
    #pragma unroll
    for (int mt = 0; mt < 4; ++mt) {
        const int mc0 = w * 64 + mt * 16 + l4 * 4;
        f32x4 b4 = *(const f32x4*)(bu1 + mc0);
        unsigned int pk0 = cvt_pk(silu_f(acc[mt][0] + b4[0]), silu_f(acc[mt][1] + b4[1]));
        unsigned int pk1 = cvt_pk(silu_f(acc[mt][2] + b4[2]), silu_f(acc[mt][3] + b4[3]));
        *(uint2*)(sm + l15 * 512 + (((mc0 >> 3) ^ (l15 & 7)) << 4) + (mc0 & 7) * 2) =
            make_uint2(pk0, pk1);
        acc[mt] = (f32x4)0.0f;
    }
    __syncthreads();

    // GEMM2': hT = Wu2T.midT
    for (int ks = 0; ks < 8; ++ks) {
        short8 anext[4];
        if (ks < 7) {
            #pragma unroll
            for (int mt = 0; mt < 4; ++mt)
                anext[mt] = *(const short8*)(Pu2 + (((ks + 1) * 16 + 4 * w + mt) * 64 + l) * 8);
        }
        short8 bfm = *(const short8*)(sm + l15 * 512 +
                        ((((ks << 2) + l4) ^ (l15 & 7)) << 4));
        #pragma unroll
        for (int mt = 0; mt < 4; ++mt)
            acc[mt] = __builtin_amdgcn_mfma_f32_16x16x32_bf16(acur[mt], bfm, acc[mt], 0, 0, 0);
        if (ks < 7) {
            #pragma unroll
            for (int mt = 0; mt < 4; ++mt) acur[mt] = anext[mt];
        }
    }

    // epilogue: float4 h stores + BN partials
    #pragma unroll
    for (int mt = 0; mt < 4; ++mt) {
        const int hc0 = w * 64 + mt * 16 + l4 * 4;
        f32x4 b4 = *(const f32x4*)(bu2 + hc0);
        const int gr = r0 + l15;
        f32x4 hv = acc[mt] + b4;
        *(f32x4*)(hout + (size_t)gr * HDIM + hc0) = hv;
        f32x4 s = hv, s2 = hv * hv;
        #pragma unroll
        for (int off = 1; off < 16; off <<= 1) {
            #pragma unroll
            for (int r = 0; r < 4; ++r) {
                s[r]  += __shfl_xor(s[r], off);
                s2[r] += __shfl_xor(s2[r], off);
            }
        }
        if (l15 == 0) {
            #pragma unroll
            for (int r = 0; r < 4; ++r) {
                atomicAdd(&sums[hc0 + r], s[r]);
                atomicAdd(&sums[HDIM + hc0 + r], s2[r]);
            }
        }
    }
}

// ---------------------------------------------------------------------------
__global__ __launch_bounds__(256) void final_kernel(
    const float* __restrict__ x, const float* __restrict__ sums,
    const float* __restrict__ gamma, const float* __restrict__ beta,
    float* __restrict__ out)
{
    const int i4 = blockIdx.x * 256 + threadIdx.x;   // float4 index
    const int j  = (i4 & 63) * 4;
    f32x4 mean = *(const f32x4*)(sums + j) * (1.0f / N_NODES);
    f32x4 s2   = *(const f32x4*)(sums + HDIM + j) * (1.0f / N_NODES);
    f32x4 g    = *(const f32x4*)(gamma + j);
    f32x4 b    = *(const f32x4*)(beta + j);
    f32x4 hv   = ((f32x4*)out)[i4];
    f32x4 xv   = ((const f32x4*)x)[i4];
    f32x4 var  = s2 - mean * mean;
    f32x4 inv;
    #pragma unroll
    for (int r = 0; r < 4; ++r) inv[r] = rsqrtf(var[r] + BN_EPS);
    ((f32x4*)out)[i4] = xv + g * (hv - mean) * inv + b;
}

extern "C" void kernel_launch(void* const* d_in, const int* in_sizes, int n_in,
                              void* d_out, int out_size, void* d_ws, size_t ws_size,
                              hipStream_t stream) {
    const float* x     = (const float*)d_in[0];
    const float* rbf   = (const float*)d_in[1];
    const int*   ei    = (const int*)d_in[2];
    const float* Wf1   = (const float*)d_in[3];
    const float* bf1   = (const float*)d_in[4];
    const float* Wf2   = (const float*)d_in[5];
    const float* bf2   = (const float*)d_in[6];
    const float* Wu1   = (const float*)d_in[7];
    const float* bu1   = (const float*)d_in[8];
    const float* Wu2   = (const float*)d_in[9];
    const float* bu2   = (const float*)d_in[10];
    const float* gamma = (const float*)d_in[11];
    const float* beta  = (const float*)d_in[12];
    float* out = (float*)d_out;

    char* ws = (char*)d_ws;
    float* agg     = (float*)(ws);                            // 10,240,000 B
    float* sums    = (float*)(ws + 10240000);                 // 2,048 B
    int*   cnt     = (int*)(ws + 10242048);                   // 40,960 B
    int*   perm    = (int*)(ws + 10283008);                   // 1,280,000 B
    int*   nodepos = (int*)(ws + 11563008);                   // 1,280,000 B
    unsigned short* Pf2 = (unsigned short*)(ws + 12843008);   // 131,072 B
    unsigned short* Pu1 = (unsigned short*)(ws + 12974080);   // 131,072 B
    unsigned short* Pu2 = (unsigned short*)(ws + 13105152);   // 131,072 B
    unsigned short* P1  = (unsigned short*)(ws + 13236224);   // 16,384 B

    // one memset covers agg + sums + cnt (contiguous)
    hipMemsetAsync(agg, 0, 10283008, stream);

    prep_hist_kernel<<<2050, 256, 0, stream>>>(Wf2, Wu1, Wu2, Wf1, bf1, ei,
                                               Pf2, Pu1, Pu2, P1, cnt);
    scan_kernel<<<1, 256, 0, stream>>>(cnt);
    fill_kernel<<<E_EDGES / 256, 256, 0, stream>>>(ei, cnt, perm, nodepos);

    edge_kernel<<<E_EDGES / 64, 256, 0, stream>>>(
        rbf, ei + E_EDGES, perm, nodepos, P1, Pf2, bf2, x, agg);
    node_kernel<<<N_NODES / RB, 256, 0, stream>>>(
        agg, bu1, bu2, Pu1, Pu2, out, sums);
    final_kernel<<<(N_NODES * HDIM / 4) / 256, 256, 0, stream>>>(
        x, sums, gamma, beta, out);
}

// Round 7
// 232.637 us; speedup vs baseline: 1.3208x; 1.0494x over previous
//
#include <hip/hip_runtime.h>

#define N_NODES 10000
#define E_EDGES 320000
#define HDIM    256
#define NG      20
#define BN_EPS  1e-5f

typedef __attribute__((ext_vector_type(8))) short short8;
typedef __attribute__((ext_vector_type(4))) float f32x4;

__device__ __forceinline__ float silu_f(float v) {
    float e = __expf(-v);
    return v * __builtin_amdgcn_rcpf(1.0f + e);
}

__device__ __forceinline__ unsigned int cvt_pk(float lo, float hi) {
    unsigned int r;
    asm("v_cvt_pk_bf16_f32 %0, %1, %2" : "=v"(r) : "v"(lo), "v"(hi));
    return r;
}

__device__ __forceinline__ unsigned short f2bf(float f) {
    union { float f; unsigned int u; } v; v.f = f;
    unsigned int r = v.u + 0x7fffu + ((v.u >> 16) & 1u);   // RNE
    return (unsigned short)(r >> 16);
}

// ---------------------------------------------------------------------------
// Fused prep (weight packing -> bf16 MFMA fragment layout) + edge histogram.
// ---------------------------------------------------------------------------
__global__ __launch_bounds__(256) void prep_hist_kernel(
    const float* __restrict__ Wf2, const float* __restrict__ Wu1,
    const float* __restrict__ Wu2, const float* __restrict__ Wf1,
    const float* __restrict__ bf1, const int* __restrict__ ei_row,
    unsigned short* __restrict__ Pf2, unsigned short* __restrict__ Pu1,
    unsigned short* __restrict__ Pu2, unsigned short* __restrict__ P1,
    int* __restrict__ cnt)
{
    const int bx = blockIdx.x;
    if (bx >= 800) {
        int e = (bx - 800) * 256 + threadIdx.x;
        atomicAdd(&cnt[ei_row[e]], 1);
        return;
    }
    int tid = bx * 256 + threadIdx.x;
    if (tid < 196608) {
        int which = tid >> 16, local = tid & 65535;
        const float* W = (which == 0) ? Wf2 : (which == 1) ? Wu1 : Wu2;
        unsigned short* P = (which == 0) ? Pf2 : (which == 1) ? Pu1 : Pu2;
        int j = local & 7, lane = (local >> 3) & 63;
        int ntile = (local >> 9) & 15, kstep = local >> 13;
        int k = kstep * 32 + (lane >> 4) * 8 + j;
        int n = ntile * 16 + (lane & 15);
        P[local] = f2bf(W[k * 256 + n]);
    } else {
        int local = tid - 196608;   // 0..8191
        int j = local & 7, lane = (local >> 3) & 63, ntile = local >> 9;
        int k = (lane >> 4) * 8 + j;
        int n = ntile * 16 + (lane & 15);
        float v = (k < NG) ? Wf1[k * 256 + n] : (k == NG ? bf1[n] : 0.0f);
        P1[local] = f2bf(v);
    }
}

// ---------------------------------------------------------------------------
// CSR build: scan + fill
// ---------------------------------------------------------------------------
__global__ __launch_bounds__(256) void scan_kernel(int* __restrict__ cnt) {
    __shared__ int tot[256];
    const int t = threadIdx.x;
    int loc[40];
    int s = 0;
    #pragma unroll
    for (int i = 0; i < 40; ++i) { loc[i] = cnt[t * 40 + i]; s += loc[i]; }
    tot[t] = s;
    __syncthreads();
    for (int off = 1; off < 256; off <<= 1) {
        int u = (t >= off) ? tot[t - off] : 0;
        __syncthreads();
        tot[t] += u;
        __syncthreads();
    }
    int pre = tot[t] - s;
    #pragma unroll
    for (int i = 0; i < 40; ++i) { int v = loc[i]; cnt[t * 40 + i] = pre; pre += v; }
}

__global__ __launch_bounds__(256) void fill_kernel(const int* __restrict__ ei_row,
                                                   int* __restrict__ cnt,
                                                   int* __restrict__ perm,
                                                   int* __restrict__ nodepos) {
    int e = blockIdx.x * 256 + threadIdx.x;
    int r = ei_row[e];
    int pos = atomicAdd(&cnt[r], 1);
    perm[pos] = e;
    nodepos[pos] = r;
}

// ---------------------------------------------------------------------------
// Edge kernel: 64 CSR-ordered edges / block, 4 waves.
// GEMM1 (swapped): hiddenT = Wf1T.rbfT; rbf staged once in LDS (80B rows).
// GEMM2 (swapped): filtT = Wf2T.hiddenT; A-frags streamed from L2 packed W.
// Epilogue: msg = (filt+bf2)*x[col] in registers; the C-fragment N index is
//   the edge index on lane&15, so 16 consecutive lanes hold 16 consecutive
//   CSR-sorted edges -> width-16 segmented shuffle scan; tail lanes atomically
//   add segment sums straight into agg. No msg LDS, no post-GEMM barriers.
// ---------------------------------------------------------------------------
#define SM_NID 0        // 64 int
#define SM_COL 256      // 64 int
#define SM_RBF 512      // [64][40] ushort rows of 80 B (5120 B)
#define SM_HID 5632     // 32768 B: hid bf16 [64][256] XOR-swizzled
#define SM_TOT 38400

__global__ __launch_bounds__(256, 3) void edge_kernel(
    const float* __restrict__ rbf, const int* __restrict__ ei_col,
    const int* __restrict__ perm, const int* __restrict__ nodepos,
    const unsigned short* __restrict__ P1, const unsigned short* __restrict__ P2,
    const float* __restrict__ bf2, const float* __restrict__ x,
    float* __restrict__ agg)
{
    __shared__ char sm[SM_TOT];
    int* nid_s = (int*)(sm + SM_NID);
    int* col_s = (int*)(sm + SM_COL);

    const int t = threadIdx.x;
    int blk = blockIdx.x;
    blk = (blk & 7) * 625 + (blk >> 3);   // XCD swizzle (5000 = 8*625, bijective)
    const int p0 = blk * 64;
    const int l = t & 63, w = t >> 6;
    const int l15 = l & 15, l4 = l >> 4;

    if (t < 64) {
        nid_s[t] = nodepos[p0 + t];
        col_s[t] = ei_col[perm[p0 + t]];
    }
    // rbf -> LDS bf16, 80 B rows; k=20 bias row (1.0), 21..31 zero
    if (t < 128) {
        const int row = t >> 1, half = t & 1;
        const float* rp = rbf + (size_t)perm[p0 + row] * NG + half * 10;
        float v[10];
        if (half == 0) {
            float4 a = *(const float4*)rp, b = *(const float4*)(rp + 4);
            float2 c = *(const float2*)(rp + 8);
            v[0]=a.x; v[1]=a.y; v[2]=a.z; v[3]=a.w; v[4]=b.x;
            v[5]=b.y; v[6]=b.z; v[7]=b.w; v[8]=c.x; v[9]=c.y;
        } else {
            float2 a = *(const float2*)rp;
            float4 b = *(const float4*)(rp + 2), c = *(const float4*)(rp + 6);
            v[0]=a.x; v[1]=a.y; v[2]=b.x; v[3]=b.y; v[4]=b.z;
            v[5]=b.w; v[6]=c.x; v[7]=c.y; v[8]=c.z; v[9]=c.w;
        }
        unsigned int* dst = (unsigned int*)(sm + SM_RBF + row * 80 + half * 20);
        #pragma unroll
        for (int i = 0; i < 5; ++i) dst[i] = cvt_pk(v[2*i], v[2*i+1]);
    } else if (t < 192) {
        const int row = t - 128;
        *(unsigned long long*)(sm + SM_RBF + row * 80 + 40) = 0x3F80ull; // 1.0,0,0,0
        *(uint4*)(sm + SM_RBF + row * 80 + 48) = make_uint4(0, 0, 0, 0);
    }

    // GEMM1 A-frags (Wf1T) and GEMM2 ks=0 A-frags (Wf2T) from global
    short8 a1[4], acur[4];
    #pragma unroll
    for (int mt = 0; mt < 4; ++mt) {
        a1[mt]   = *(const short8*)(P1 + ((4 * w + mt) * 64 + l) * 8);
        acur[mt] = *(const short8*)(P2 + ((4 * w + mt) * 64 + l) * 8);
    }

    __syncthreads();

    const float* xbase[4];
    #pragma unroll
    for (int nt = 0; nt < 4; ++nt)
        xbase[nt] = x + (size_t)col_s[nt * 16 + l15] * HDIM;

    f32x4 acc[4][4];   // [mt][nt]
    #pragma unroll
    for (int mt = 0; mt < 4; ++mt)
        #pragma unroll
        for (int nt = 0; nt < 4; ++nt) acc[mt][nt] = (f32x4)0.0f;

    // GEMM1: one K=32 step; B = rbfT from LDS (stride 80B)
    #pragma unroll
    for (int nt = 0; nt < 4; ++nt) {
        short8 bfr = *(const short8*)(sm + SM_RBF + (nt * 16 + l15) * 80 + l4 * 16);
        #pragma unroll
        for (int mt = 0; mt < 4; ++mt)
            acc[mt][nt] = __builtin_amdgcn_mfma_f32_16x16x32_bf16(a1[mt], bfr, acc[mt][nt], 0, 0, 0);
    }

    // silu -> hid bf16, XOR-swizzled, b64 stores
    #pragma unroll
    for (int mt = 0; mt < 4; ++mt) {
        const int hc0 = w * 64 + mt * 16 + l4 * 4;
        #pragma unroll
        for (int nt = 0; nt < 4; ++nt) {
            const int row = nt * 16 + l15;
            unsigned int pk0 = cvt_pk(silu_f(acc[mt][nt][0]), silu_f(acc[mt][nt][1]));
            unsigned int pk1 = cvt_pk(silu_f(acc[mt][nt][2]), silu_f(acc[mt][nt][3]));
            *(uint2*)(sm + SM_HID + row * 512 +
                      (((hc0 >> 3) ^ (row & 7)) << 4) + (hc0 & 7) * 2) =
                make_uint2(pk0, pk1);
        }
    }
    __syncthreads();

    // GEMM2: filtT = Wf2T.hiddenT; x prefetch for edge rows 0..31 at ks==6
    #pragma unroll
    for (int mt = 0; mt < 4; ++mt)
        #pragma unroll
        for (int nt = 0; nt < 4; ++nt) acc[mt][nt] = (f32x4)0.0f;

    f32x4 xp[8];   // x fragments for nt=0 (xp[0..3]) and nt=1 (xp[4..7])

    for (int ks = 0; ks < 8; ++ks) {
        short8 anext[4];
        if (ks < 7) {
            #pragma unroll
            for (int mt = 0; mt < 4; ++mt)
                anext[mt] = *(const short8*)(P2 + (((ks + 1) * 16 + 4 * w + mt) * 64 + l) * 8);
        }
        if (ks == 6) {
            #pragma unroll
            for (int mt = 0; mt < 4; ++mt) {
                const int fc0 = w * 64 + mt * 16 + l4 * 4;
                xp[mt]     = *(const f32x4*)(xbase[0] + fc0);
                xp[4 + mt] = *(const f32x4*)(xbase[1] + fc0);
            }
        }
        #pragma unroll
        for (int nt = 0; nt < 4; ++nt) {
            const int row = nt * 16 + l15;
            short8 bfh = *(const short8*)(sm + SM_HID + row * 512 +
                            ((((ks << 2) + l4) ^ (row & 7)) << 4));
            #pragma unroll
            for (int mt = 0; mt < 4; ++mt)
                acc[mt][nt] = __builtin_amdgcn_mfma_f32_16x16x32_bf16(acur[mt], bfh, acc[mt][nt], 0, 0, 0);
        }
        if (ks < 7) {
            #pragma unroll
            for (int mt = 0; mt < 4; ++mt) acur[mt] = anext[mt];
        }
    }
    // NO barrier: hid LDS is not read again.

    f32x4 bc4[4];
    #pragma unroll
    for (int mt = 0; mt < 4; ++mt)
        bc4[mt] = *(const f32x4*)(bf2 + w * 64 + mt * 16 + l4 * 4);

    // msg for nt=0,1 in place (xp dies), then issue x loads for nt=2,3
    #pragma unroll
    for (int nt = 0; nt < 2; ++nt)
        #pragma unroll
        for (int mt = 0; mt < 4; ++mt)
            acc[mt][nt] = (acc[mt][nt] + bc4[mt]) * xp[nt * 4 + mt];

    f32x4 xq[8];
    #pragma unroll
    for (int mt = 0; mt < 4; ++mt) {
        const int fc0 = w * 64 + mt * 16 + l4 * 4;
        xq[mt]     = *(const f32x4*)(xbase[2] + fc0);
        xq[4 + mt] = *(const f32x4*)(xbase[3] + fc0);
    }

    // width-16 segmented shuffle scan + tail-lane atomics, per nt group
    #pragma unroll
    for (int nt = 0; nt < 4; ++nt) {
        if (nt >= 2) {   // msg for nt=2,3 (xq latency covered by nt=0,1 scans)
            #pragma unroll
            for (int mt = 0; mt < 4; ++mt)
                acc[mt][nt] = (acc[mt][nt] + bc4[mt]) * xq[(nt - 2) * 4 + mt];
        }
        const int erow = nt * 16 + l15;
        const int nid   = nid_s[erow];
        const int nprev = __shfl_up(nid, 1, 16);
        const int nnext = __shfl_down(nid, 1, 16);
        unsigned f = (l15 == 0 || nid != nprev) ? 1u : 0u;
        const bool tail = (l15 == 15) || (nid != nnext);

        #pragma unroll
        for (int s = 1; s < 16; s <<= 1) {
            unsigned ff = __shfl_up(f, s, 16);
            f32x4 vv[4];
            #pragma unroll
            for (int mt = 0; mt < 4; ++mt)
                #pragma unroll
                for (int r = 0; r < 4; ++r)
                    vv[mt][r] = __shfl_up(acc[mt][nt][r], s, 16);
            if (l15 >= s && !f) {
                #pragma unroll
                for (int mt = 0; mt < 4; ++mt) acc[mt][nt] += vv[mt];
                f = ff;
            }
        }
        if (tail) {
            float* ap = agg + (size_t)nid * HDIM;
            #pragma unroll
            for (int mt = 0; mt < 4; ++mt) {
                const int fc0 = w * 64 + mt * 16 + l4 * 4;
                #pragma unroll
                for (int r = 0; r < 4; ++r)
                    atomicAdd(ap + fc0 + r, acc[mt][nt][r]);
            }
        }
    }
}

// ---------------------------------------------------------------------------
// Node kernel (round-4 structure): 64 rows/block, both GEMMs swapped,
// fused BN partials. LDS 32KB.
// ---------------------------------------------------------------------------
__global__ __launch_bounds__(256, 3) void node_kernel(
    const float* __restrict__ agg, const float* __restrict__ bu1,
    const float* __restrict__ bu2,
    const unsigned short* __restrict__ Pu1, const unsigned short* __restrict__ Pu2,
    float* __restrict__ hout, float* __restrict__ sums)
{
    __shared__ char sm[32768];    // [64 nodes][256] bf16, XOR-swizzled
    const int t  = threadIdx.x;
    const int r0 = blockIdx.x * 64;
    const int l = t & 63, w = t >> 6;
    const int l15 = l & 15, l4 = l >> 4;

    // stage agg -> LDS bf16 (float4 + cvt_pk + b64)
    {
        const int row = t & 63, q = t >> 6;
        const bool valid = (r0 + row) < N_NODES;
        const float4* src = (const float4*)(agg + (size_t)(r0 + row) * HDIM) + q * 16;
        #pragma unroll
        for (int i = 0; i < 16; ++i) {
            float4 v = valid ? src[i] : make_float4(0.f, 0.f, 0.f, 0.f);
            const int c0 = q * 64 + i * 4;
            *(uint2*)(sm + row * 512 + (((c0 >> 3) ^ (row & 7)) << 4) + (c0 & 7) * 2) =
                make_uint2(cvt_pk(v.x, v.y), cvt_pk(v.z, v.w));
        }
    }

    short8 acur[4];
    #pragma unroll
    for (int mt = 0; mt < 4; ++mt)
        acur[mt] = *(const short8*)(Pu1 + ((4 * w + mt) * 64 + l) * 8);

    __syncthreads();

    f32x4 acc[4][4];
    #pragma unroll
    for (int mt = 0; mt < 4; ++mt)
        #pragma unroll
        for (int nt = 0; nt < 4; ++nt) acc[mt][nt] = (f32x4)0.0f;

    // GEMM1': midT = Wu1T.aggT
    for (int ks = 0; ks < 8; ++ks) {
        short8 anext[4];
        if (ks < 7) {
            #pragma unroll
            for (int mt = 0; mt < 4; ++mt)
                anext[mt] = *(const short8*)(Pu1 + (((ks + 1) * 16 + 4 * w + mt) * 64 + l) * 8);
        }
        #pragma unroll
        for (int nt = 0; nt < 4; ++nt) {
            const int row = nt * 16 + l15;
            short8 bfa = *(const short8*)(sm + row * 512 +
                            ((((ks << 2) + l4) ^ (row & 7)) << 4));
            #pragma unroll
            for (int mt = 0; mt < 4; ++mt)
                acc[mt][nt] = __builtin_amdgcn_mfma_f32_16x16x32_bf16(acur[mt], bfa, acc[mt][nt], 0, 0, 0);
        }
        if (ks < 7) {
            #pragma unroll
            for (int mt = 0; mt < 4; ++mt) acur[mt] = anext[mt];
        }
    }
    __syncthreads();   // all reads done; overwrite with mid

    #pragma unroll
    for (int mt = 0; mt < 4; ++mt)
        acur[mt] = *(const short8*)(Pu2 + ((4 * w + mt) * 64 + l) * 8);

    // mid = silu(acc + bu1) -> LDS (b64 stores)
    #pragma unroll
    for (int mt = 0; mt < 4; ++mt) {
        const int mc0 = w * 64 + mt * 16 + l4 * 4;
        f32x4 b4 = *(const f32x4*)(bu1 + mc0);
        #pragma unroll
        for (int nt = 0; nt < 4; ++nt) {
            const int row = nt * 16 + l15;
            unsigned int pk0 = cvt_pk(silu_f(acc[mt][nt][0] + b4[0]), silu_f(acc[mt][nt][1] + b4[1]));
            unsigned int pk1 = cvt_pk(silu_f(acc[mt][nt][2] + b4[2]), silu_f(acc[mt][nt][3] + b4[3]));
            *(uint2*)(sm + row * 512 + (((mc0 >> 3) ^ (row & 7)) << 4) + (mc0 & 7) * 2) =
                make_uint2(pk0, pk1);
            acc[mt][nt] = (f32x4)0.0f;
        }
    }
    __syncthreads();

    // GEMM2': hT = Wu2T.midT
    for (int ks = 0; ks < 8; ++ks) {
        short8 anext[4];
        if (ks < 7) {
            #pragma unroll
            for (int mt = 0; mt < 4; ++mt)
                anext[mt] = *(const short8*)(Pu2 + (((ks + 1) * 16 + 4 * w + mt) * 64 + l) * 8);
        }
        #pragma unroll
        for (int nt = 0; nt < 4; ++nt) {
            const int row = nt * 16 + l15;
            short8 bfm = *(const short8*)(sm + row * 512 +
                            ((((ks << 2) + l4) ^ (row & 7)) << 4));
            #pragma unroll
            for (int mt = 0; mt < 4; ++mt)
                acc[mt][nt] = __builtin_amdgcn_mfma_f32_16x16x32_bf16(acur[mt], bfm, acc[mt][nt], 0, 0, 0);
        }
        if (ks < 7) {
            #pragma unroll
            for (int mt = 0; mt < 4; ++mt) acur[mt] = anext[mt];
        }
    }

    // epilogue: float4 h stores + BN partials
    #pragma unroll
    for (int mt = 0; mt < 4; ++mt) {
        const int hc0 = w * 64 + mt * 16 + l4 * 4;
        f32x4 b4 = *(const f32x4*)(bu2 + hc0);
        f32x4 s = (f32x4)0.0f, s2 = (f32x4)0.0f;
        #pragma unroll
        for (int nt = 0; nt < 4; ++nt) {
            const int gr = r0 + nt * 16 + l15;
            if (gr < N_NODES) {
                f32x4 hv = acc[mt][nt] + b4;
                *(f32x4*)(hout + (size_t)gr * HDIM + hc0) = hv;
                s += hv; s2 += hv * hv;
            }
        }
        #pragma unroll
        for (int off = 1; off < 16; off <<= 1) {
            #pragma unroll
            for (int r = 0; r < 4; ++r) {
                s[r]  += __shfl_xor(s[r], off);
                s2[r] += __shfl_xor(s2[r], off);
            }
        }
        if (l15 == 0) {
            #pragma unroll
            for (int r = 0; r < 4; ++r) {
                atomicAdd(&sums[hc0 + r], s[r]);
                atomicAdd(&sums[HDIM + hc0 + r], s2[r]);
            }
        }
    }
}

// ---------------------------------------------------------------------------
__global__ __launch_bounds__(256) void final_kernel(
    const float* __restrict__ x, const float* __restrict__ sums,
    const float* __restrict__ gamma, const float* __restrict__ beta,
    float* __restrict__ out)
{
    const int i4 = blockIdx.x * 256 + threadIdx.x;   // float4 index
    const int j  = (i4 & 63) * 4;
    f32x4 mean = *(const f32x4*)(sums + j) * (1.0f / N_NODES);
    f32x4 s2   = *(const f32x4*)(sums + HDIM + j) * (1.0f / N_NODES);
    f32x4 g    = *(const f32x4*)(gamma + j);
    f32x4 b    = *(const f32x4*)(beta + j);
    f32x4 hv   = ((f32x4*)out)[i4];
    f32x4 xv   = ((const f32x4*)x)[i4];
    f32x4 var  = s2 - mean * mean;
    f32x4 inv;
    #pragma unroll
    for (int r = 0; r < 4; ++r) inv[r] = rsqrtf(var[r] + BN_EPS);
    ((f32x4*)out)[i4] = xv + g * (hv - mean) * inv + b;
}

extern "C" void kernel_launch(void* const* d_in, const int* in_sizes, int n_in,
                              void* d_out, int out_size, void* d_ws, size_t ws_size,
                              hipStream_t stream) {
    const float* x     = (const float*)d_in[0];
    const float* rbf   = (const float*)d_in[1];
    const int*   ei    = (const int*)d_in[2];
    const float* Wf1   = (const float*)d_in[3];
    const float* bf1   = (const float*)d_in[4];
    const float* Wf2   = (const float*)d_in[5];
    const float* bf2   = (const float*)d_in[6];
    const float* Wu1   = (const float*)d_in[7];
    const float* bu1   = (const float*)d_in[8];
    const float* Wu2   = (const float*)d_in[9];
    const float* bu2   = (const float*)d_in[10];
    const float* gamma = (const float*)d_in[11];
    const float* beta  = (const float*)d_in[12];
    float* out = (float*)d_out;

    char* ws = (char*)d_ws;
    float* agg     = (float*)(ws);                            // 10,240,000 B
    float* sums    = (float*)(ws + 10240000);                 // 2,048 B
    int*   cnt     = (int*)(ws + 10242048);                   // 40,960 B
    int*   perm    = (int*)(ws + 10283008);                   // 1,280,000 B
    int*   nodepos = (int*)(ws + 11563008);                   // 1,280,000 B
    unsigned short* Pf2 = (unsigned short*)(ws + 12843008);   // 131,072 B
    unsigned short* Pu1 = (unsigned short*)(ws + 12974080);   // 131,072 B
    unsigned short* Pu2 = (unsigned short*)(ws + 13105152);   // 131,072 B
    unsigned short* P1  = (unsigned short*)(ws + 13236224);   // 16,384 B

    // one memset covers agg + sums + cnt (contiguous)
    hipMemsetAsync(agg, 0, 10283008, stream);

    prep_hist_kernel<<<2050, 256, 0, stream>>>(Wf2, Wu1, Wu2, Wf1, bf1, ei,
                                               Pf2, Pu1, Pu2, P1, cnt);
    scan_kernel<<<1, 256, 0, stream>>>(cnt);
    fill_kernel<<<E_EDGES / 256, 256, 0, stream>>>(ei, cnt, perm, nodepos);

    edge_kernel<<<E_EDGES / 64, 256, 0, stream>>>(
        rbf, ei + E_EDGES, perm, nodepos, P1, Pf2, bf2, x, agg);
    node_kernel<<<(N_NODES + 63) / 64, 256, 0, stream>>>(
        agg, bu1, bu2, Pu1, Pu2, out, sums);
    final_kernel<<<(N_NODES * HDIM / 4) / 256, 256, 0, stream>>>(
        x, sums, gamma, beta, out);
}

// Round 8
// 201.716 us; speedup vs baseline: 1.5232x; 1.1533x over previous
//
#include <hip/hip_runtime.h>

#define N_NODES 10000
#define E_EDGES 320000
#define HDIM    256
#define NG      20
#define BN_EPS  1e-5f

typedef __attribute__((ext_vector_type(8))) short short8;
typedef __attribute__((ext_vector_type(4))) float f32x4;

__device__ __forceinline__ float silu_f(float v) {
    float e = __expf(-v);
    return v * __builtin_amdgcn_rcpf(1.0f + e);
}

__device__ __forceinline__ unsigned int cvt_pk(float lo, float hi) {
    unsigned int r;
    asm("v_cvt_pk_bf16_f32 %0, %1, %2" : "=v"(r) : "v"(lo), "v"(hi));
    return r;
}

__device__ __forceinline__ unsigned short f2bf(float f) {
    union { float f; unsigned int u; } v; v.f = f;
    unsigned int r = v.u + 0x7fffu + ((v.u >> 16) & 1u);   // RNE
    return (unsigned short)(r >> 16);
}

// ---------------------------------------------------------------------------
// Fused prep (weight packing -> bf16 MFMA fragment layout) + edge histogram.
// ---------------------------------------------------------------------------
__global__ __launch_bounds__(256) void prep_hist_kernel(
    const float* __restrict__ Wf2, const float* __restrict__ Wu1,
    const float* __restrict__ Wu2, const float* __restrict__ Wf1,
    const float* __restrict__ bf1, const int* __restrict__ ei_row,
    unsigned short* __restrict__ Pf2, unsigned short* __restrict__ Pu1,
    unsigned short* __restrict__ Pu2, unsigned short* __restrict__ P1,
    int* __restrict__ cnt)
{
    const int bx = blockIdx.x;
    if (bx >= 800) {
        int e = (bx - 800) * 256 + threadIdx.x;
        atomicAdd(&cnt[ei_row[e]], 1);
        return;
    }
    int tid = bx * 256 + threadIdx.x;
    if (tid < 196608) {
        int which = tid >> 16, local = tid & 65535;
        const float* W = (which == 0) ? Wf2 : (which == 1) ? Wu1 : Wu2;
        unsigned short* P = (which == 0) ? Pf2 : (which == 1) ? Pu1 : Pu2;
        int j = local & 7, lane = (local >> 3) & 63;
        int ntile = (local >> 9) & 15, kstep = local >> 13;
        int k = kstep * 32 + (lane >> 4) * 8 + j;
        int n = ntile * 16 + (lane & 15);
        P[local] = f2bf(W[k * 256 + n]);
    } else {
        int local = tid - 196608;   // 0..8191
        int j = local & 7, lane = (local >> 3) & 63, ntile = local >> 9;
        int k = (lane >> 4) * 8 + j;
        int n = ntile * 16 + (lane & 15);
        float v = (k < NG) ? Wf1[k * 256 + n] : (k == NG ? bf1[n] : 0.0f);
        P1[local] = f2bf(v);
    }
}

// ---------------------------------------------------------------------------
// CSR build: scan + fill
// ---------------------------------------------------------------------------
__global__ __launch_bounds__(256) void scan_kernel(int* __restrict__ cnt) {
    __shared__ int tot[256];
    const int t = threadIdx.x;
    int loc[40];
    int s = 0;
    #pragma unroll
    for (int i = 0; i < 40; ++i) { loc[i] = cnt[t * 40 + i]; s += loc[i]; }
    tot[t] = s;
    __syncthreads();
    for (int off = 1; off < 256; off <<= 1) {
        int u = (t >= off) ? tot[t - off] : 0;
        __syncthreads();
        tot[t] += u;
        __syncthreads();
    }
    int pre = tot[t] - s;
    #pragma unroll
    for (int i = 0; i < 40; ++i) { int v = loc[i]; cnt[t * 40 + i] = pre; pre += v; }
}

__global__ __launch_bounds__(256) void fill_kernel(const int* __restrict__ ei_row,
                                                   int* __restrict__ cnt,
                                                   int* __restrict__ perm,
                                                   int* __restrict__ nodepos) {
    int e = blockIdx.x * 256 + threadIdx.x;
    int r = ei_row[e];
    int pos = atomicAdd(&cnt[r], 1);
    perm[pos] = e;
    nodepos[pos] = r;
}

// ---------------------------------------------------------------------------
// Edge kernel: 64 CSR-ordered edges / block, 4 waves, 4 blocks/CU.
// GEMM1 (swapped): hiddenT = Wf1T.rbfT; rbf staged once in LDS (80B rows).
// GEMM2 (swapped): filtT = Wf2T.hiddenT; A-frags streamed from L2 packed W.
// msg = (filt+bf2)*x[col] -> f32 LDS overlay (2 passes), serial segmented
// column reduce, contiguous per-node-row atomics into agg.
// Register budget kept <=128 total (64 acc AGPR + ~50 VGPR) for 4 waves/SIMD:
// pass-0 x loads are inline; pass-1 x prefetched during pass-0 reduce where
// half the accumulators are dead.
// ---------------------------------------------------------------------------
#define SM_NID 0        // 64 int
#define SM_COL 256      // 64 int
#define SM_RBF 512      // [64][40] ushort rows of 80 B (5120 B)
#define SM_HID 5632     // 32768 B: hid bf16 [64][256] swz / msg f32 [32][256] swz
#define SM_TOT 38400

__global__ __launch_bounds__(256, 4) void edge_kernel(
    const float* __restrict__ rbf, const int* __restrict__ ei_col,
    const int* __restrict__ perm, const int* __restrict__ nodepos,
    const unsigned short* __restrict__ P1, const unsigned short* __restrict__ P2,
    const float* __restrict__ bf2, const float* __restrict__ x,
    float* __restrict__ agg)
{
    __shared__ char sm[SM_TOT];
    int* nid_s = (int*)(sm + SM_NID);
    int* col_s = (int*)(sm + SM_COL);

    const int t = threadIdx.x;
    int blk = blockIdx.x;
    blk = (blk & 7) * 625 + (blk >> 3);   // XCD swizzle (5000 = 8*625, bijective)
    const int p0 = blk * 64;
    const int l = t & 63, w = t >> 6;
    const int l15 = l & 15, l4 = l >> 4;

    if (t < 64) {
        nid_s[t] = nodepos[p0 + t];
        col_s[t] = ei_col[perm[p0 + t]];
    }
    // rbf -> LDS bf16, 80 B rows; k=20 bias row (1.0), 21..31 zero
    if (t < 128) {
        const int row = t >> 1, half = t & 1;
        const float* rp = rbf + (size_t)perm[p0 + row] * NG + half * 10;
        float v[10];
        if (half == 0) {
            float4 a = *(const float4*)rp, b = *(const float4*)(rp + 4);
            float2 c = *(const float2*)(rp + 8);
            v[0]=a.x; v[1]=a.y; v[2]=a.z; v[3]=a.w; v[4]=b.x;
            v[5]=b.y; v[6]=b.z; v[7]=b.w; v[8]=c.x; v[9]=c.y;
        } else {
            float2 a = *(const float2*)rp;
            float4 b = *(const float4*)(rp + 2), c = *(const float4*)(rp + 6);
            v[0]=a.x; v[1]=a.y; v[2]=b.x; v[3]=b.y; v[4]=b.z;
            v[5]=b.w; v[6]=c.x; v[7]=c.y; v[8]=c.z; v[9]=c.w;
        }
        unsigned int* dst = (unsigned int*)(sm + SM_RBF + row * 80 + half * 20);
        #pragma unroll
        for (int i = 0; i < 5; ++i) dst[i] = cvt_pk(v[2*i], v[2*i+1]);
    } else if (t < 192) {
        const int row = t - 128;
        *(unsigned long long*)(sm + SM_RBF + row * 80 + 40) = 0x3F80ull; // 1.0,0,0,0
        *(uint4*)(sm + SM_RBF + row * 80 + 48) = make_uint4(0, 0, 0, 0);
    }

    // GEMM1 A-frags (Wf1T) and GEMM2 ks=0 A-frags (Wf2T) from global
    short8 a1[4], acur[4];
    #pragma unroll
    for (int mt = 0; mt < 4; ++mt) {
        a1[mt]   = *(const short8*)(P1 + ((4 * w + mt) * 64 + l) * 8);
        acur[mt] = *(const short8*)(P2 + ((4 * w + mt) * 64 + l) * 8);
    }

    __syncthreads();

    f32x4 acc[4][4];   // [mt][nt]
    #pragma unroll
    for (int mt = 0; mt < 4; ++mt)
        #pragma unroll
        for (int nt = 0; nt < 4; ++nt) acc[mt][nt] = (f32x4)0.0f;

    // GEMM1: one K=32 step; B = rbfT from LDS (stride 80B)
    #pragma unroll
    for (int nt = 0; nt < 4; ++nt) {
        short8 bfr = *(const short8*)(sm + SM_RBF + (nt * 16 + l15) * 80 + l4 * 16);
        #pragma unroll
        for (int mt = 0; mt < 4; ++mt)
            acc[mt][nt] = __builtin_amdgcn_mfma_f32_16x16x32_bf16(a1[mt], bfr, acc[mt][nt], 0, 0, 0);
    }

    // silu -> hid bf16, XOR-swizzled, b64 stores
    #pragma unroll
    for (int mt = 0; mt < 4; ++mt) {
        const int hc0 = w * 64 + mt * 16 + l4 * 4;
        #pragma unroll
        for (int nt = 0; nt < 4; ++nt) {
            const int row = nt * 16 + l15;
            unsigned int pk0 = cvt_pk(silu_f(acc[mt][nt][0]), silu_f(acc[mt][nt][1]));
            unsigned int pk1 = cvt_pk(silu_f(acc[mt][nt][2]), silu_f(acc[mt][nt][3]));
            *(uint2*)(sm + SM_HID + row * 512 +
                      (((hc0 >> 3) ^ (row & 7)) << 4) + (hc0 & 7) * 2) =
                make_uint2(pk0, pk1);
        }
    }
    __syncthreads();

    // GEMM2: filtT = Wf2T.hiddenT (no x prefetch inside: keeps VGPR <= 128)
    #pragma unroll
    for (int mt = 0; mt < 4; ++mt)
        #pragma unroll
        for (int nt = 0; nt < 4; ++nt) acc[mt][nt] = (f32x4)0.0f;

    for (int ks = 0; ks < 8; ++ks) {
        short8 anext[4];
        if (ks < 7) {
            #pragma unroll
            for (int mt = 0; mt < 4; ++mt)
                anext[mt] = *(const short8*)(P2 + (((ks + 1) * 16 + 4 * w + mt) * 64 + l) * 8);
        }
        #pragma unroll
        for (int nt = 0; nt < 4; ++nt) {
            const int row = nt * 16 + l15;
            short8 bfh = *(const short8*)(sm + SM_HID + row * 512 +
                            ((((ks << 2) + l4) ^ (row & 7)) << 4));
            #pragma unroll
            for (int mt = 0; mt < 4; ++mt)
                acc[mt][nt] = __builtin_amdgcn_mfma_f32_16x16x32_bf16(acur[mt], bfh, acc[mt][nt], 0, 0, 0);
        }
        if (ks < 7) {
            #pragma unroll
            for (int mt = 0; mt < 4; ++mt) acur[mt] = anext[mt];
        }
    }
    __syncthreads();   // all hid reads done -> msg overlay

    f32x4 bc4[4];
    #pragma unroll
    for (int mt = 0; mt < 4; ++mt)
        bc4[mt] = *(const f32x4*)(bf2 + w * 64 + mt * 16 + l4 * 4);

    const float* xbase[4];
    #pragma unroll
    for (int nt = 0; nt < 4; ++nt)
        xbase[nt] = x + (size_t)col_s[nt * 16 + l15] * HDIM;

    float sum = 0.0f;
    int cur = nid_s[0];

    // ---- pass 0: edge rows 0..31 (x loaded inline) ----
    {
        f32x4 xp[8];
        #pragma unroll
        for (int mt = 0; mt < 4; ++mt) {
            const int fc0 = w * 64 + mt * 16 + l4 * 4;
            xp[mt]     = *(const f32x4*)(xbase[0] + fc0);
            xp[4 + mt] = *(const f32x4*)(xbase[1] + fc0);
        }
        #pragma unroll
        for (int ni = 0; ni < 2; ++ni) {
            const int pos = ni * 16 + l15;
            #pragma unroll
            for (int mt = 0; mt < 4; ++mt) {
                const int fc0 = w * 64 + mt * 16 + l4 * 4;
                f32x4 mv = (acc[mt][ni] + bc4[mt]) * xp[ni * 4 + mt];
                *(f32x4*)(sm + SM_HID + pos * 1024 + (((fc0 >> 2) ^ (pos & 7)) << 4)) = mv;
            }
        }
    }
    // prefetch x for pass 1 (latency hidden under reduce pass 0; acc[..][0,1] dead)
    f32x4 xq[8];
    #pragma unroll
    for (int mt = 0; mt < 4; ++mt) {
        const int fc0 = w * 64 + mt * 16 + l4 * 4;
        xq[mt]     = *(const f32x4*)(xbase[2] + fc0);
        xq[4 + mt] = *(const f32x4*)(xbase[3] + fc0);
    }
    __syncthreads();
    for (int pos = 0; pos < 32; ++pos) {
        const int nid = nid_s[pos];
        float v = *(const float*)(sm + SM_HID + pos * 1024 +
                    (((t >> 2) ^ (pos & 7)) << 4) + (t & 3) * 4);
        if (nid != cur) {
            atomicAdd(&agg[(size_t)cur * HDIM + t], sum);
            sum = 0.0f; cur = nid;
        }
        sum += v;
    }
    __syncthreads();

    // ---- pass 1: edge rows 32..63 ----
    #pragma unroll
    for (int ni = 0; ni < 2; ++ni) {
        const int nt  = 2 + ni;
        const int pos = ni * 16 + l15;
        #pragma unroll
        for (int mt = 0; mt < 4; ++mt) {
            const int fc0 = w * 64 + mt * 16 + l4 * 4;
            f32x4 mv = (acc[mt][nt] + bc4[mt]) * xq[ni * 4 + mt];
            *(f32x4*)(sm + SM_HID + pos * 1024 + (((fc0 >> 2) ^ (pos & 7)) << 4)) = mv;
        }
    }
    __syncthreads();
    for (int pos = 0; pos < 32; ++pos) {
        const int nid = nid_s[32 + pos];
        float v = *(const float*)(sm + SM_HID + pos * 1024 +
                    (((t >> 2) ^ (pos & 7)) << 4) + (t & 3) * 4);
        if (nid != cur) {
            atomicAdd(&agg[(size_t)cur * HDIM + t], sum);
            sum = 0.0f; cur = nid;
        }
        sum += v;
    }
    atomicAdd(&agg[(size_t)cur * HDIM + t], sum);
}

// ---------------------------------------------------------------------------
// Node kernel (round-4 structure): 64 rows/block, both GEMMs swapped,
// fused BN partials. LDS 32KB.
// ---------------------------------------------------------------------------
__global__ __launch_bounds__(256, 3) void node_kernel(
    const float* __restrict__ agg, const float* __restrict__ bu1,
    const float* __restrict__ bu2,
    const unsigned short* __restrict__ Pu1, const unsigned short* __restrict__ Pu2,
    float* __restrict__ hout, float* __restrict__ sums)
{
    __shared__ char sm[32768];    // [64 nodes][256] bf16, XOR-swizzled
    const int t  = threadIdx.x;
    const int r0 = blockIdx.x * 64;
    const int l = t & 63, w = t >> 6;
    const int l15 = l & 15, l4 = l >> 4;

    // stage agg -> LDS bf16 (float4 + cvt_pk + b64)
    {
        const int row = t & 63, q = t >> 6;
        const bool valid = (r0 + row) < N_NODES;
        const float4* src = (const float4*)(agg + (size_t)(r0 + row) * HDIM) + q * 16;
        #pragma unroll
        for (int i = 0; i < 16; ++i) {
            float4 v = valid ? src[i] : make_float4(0.f, 0.f, 0.f, 0.f);
            const int c0 = q * 64 + i * 4;
            *(uint2*)(sm + row * 512 + (((c0 >> 3) ^ (row & 7)) << 4) + (c0 & 7) * 2) =
                make_uint2(cvt_pk(v.x, v.y), cvt_pk(v.z, v.w));
        }
    }

    short8 acur[4];
    #pragma unroll
    for (int mt = 0; mt < 4; ++mt)
        acur[mt] = *(const short8*)(Pu1 + ((4 * w + mt) * 64 + l) * 8);

    __syncthreads();

    f32x4 acc[4][4];
    #pragma unroll
    for (int mt = 0; mt < 4; ++mt)
        #pragma unroll
        for (int nt = 0; nt < 4; ++nt) acc[mt][nt] = (f32x4)0.0f;

    // GEMM1': midT = Wu1T.aggT
    for (int ks = 0; ks < 8; ++ks) {
        short8 anext[4];
        if (ks < 7) {
            #pragma unroll
            for (int mt = 0; mt < 4; ++mt)
                anext[mt] = *(const short8*)(Pu1 + (((ks + 1) * 16 + 4 * w + mt) * 64 + l) * 8);
        }
        #pragma unroll
        for (int nt = 0; nt < 4; ++nt) {
            const int row = nt * 16 + l15;
            short8 bfa = *(const short8*)(sm + row * 512 +
                            ((((ks << 2) + l4) ^ (row & 7)) << 4));
            #pragma unroll
            for (int mt = 0; mt < 4; ++mt)
                acc[mt][nt] = __builtin_amdgcn_mfma_f32_16x16x32_bf16(acur[mt], bfa, acc[mt][nt], 0, 0, 0);
        }
        if (ks < 7) {
            #pragma unroll
            for (int mt = 0; mt < 4; ++mt) acur[mt] = anext[mt];
        }
    }
    __syncthreads();   // all reads done; overwrite with mid

    #pragma unroll
    for (int mt = 0; mt < 4; ++mt)
        acur[mt] = *(const short8*)(Pu2 + ((4 * w + mt) * 64 + l) * 8);

    // mid = silu(acc + bu1) -> LDS (b64 stores)
    #pragma unroll
    for (int mt = 0; mt < 4; ++mt) {
        const int mc0 = w * 64 + mt * 16 + l4 * 4;
        f32x4 b4 = *(const f32x4*)(bu1 + mc0);
        #pragma unroll
        for (int nt = 0; nt < 4; ++nt) {
            const int row = nt * 16 + l15;
            unsigned int pk0 = cvt_pk(silu_f(acc[mt][nt][0] + b4[0]), silu_f(acc[mt][nt][1] + b4[1]));
            unsigned int pk1 = cvt_pk(silu_f(acc[mt][nt][2] + b4[2]), silu_f(acc[mt][nt][3] + b4[3]));
            *(uint2*)(sm + row * 512 + (((mc0 >> 3) ^ (row & 7)) << 4) + (mc0 & 7) * 2) =
                make_uint2(pk0, pk1);
            acc[mt][nt] = (f32x4)0.0f;
        }
    }
    __syncthreads();

    // GEMM2': hT = Wu2T.midT
    for (int ks = 0; ks < 8; ++ks) {
        short8 anext[4];
        if (ks < 7) {
            #pragma unroll
            for (int mt = 0; mt < 4; ++mt)
                anext[mt] = *(const short8*)(Pu2 + (((ks + 1) * 16 + 4 * w + mt) * 64 + l) * 8);
        }
        #pragma unroll
        for (int nt = 0; nt < 4; ++nt) {
            const int row = nt * 16 + l15;
            short8 bfm = *(const short8*)(sm + row * 512 +
                            ((((ks << 2) + l4) ^ (row & 7)) << 4));
            #pragma unroll
            for (int mt = 0; mt < 4; ++mt)
                acc[mt][nt] = __builtin_amdgcn_mfma_f32_16x16x32_bf16(acur[mt], bfm, acc[mt][nt], 0, 0, 0);
        }
        if (ks < 7) {
            #pragma unroll
            for (int mt = 0; mt < 4; ++mt) acur[mt] = anext[mt];
        }
    }

    // epilogue: float4 h stores + BN partials
    #pragma unroll
    for (int mt = 0; mt < 4; ++mt) {
        const int hc0 = w * 64 + mt * 16 + l4 * 4;
        f32x4 b4 = *(const f32x4*)(bu2 + hc0);
        f32x4 s = (f32x4)0.0f, s2 = (f32x4)0.0f;
        #pragma unroll
        for (int nt = 0; nt < 4; ++nt) {
            const int gr = r0 + nt * 16 + l15;
            if (gr < N_NODES) {
                f32x4 hv = acc[mt][nt] + b4;
                *(f32x4*)(hout + (size_t)gr * HDIM + hc0) = hv;
                s += hv; s2 += hv * hv;
            }
        }
        #pragma unroll
        for (int off = 1; off < 16; off <<= 1) {
            #pragma unroll
            for (int r = 0; r < 4; ++r) {
                s[r]  += __shfl_xor(s[r], off);
                s2[r] += __shfl_xor(s2[r], off);
            }
        }
        if (l15 == 0) {
            #pragma unroll
            for (int r = 0; r < 4; ++r) {
                atomicAdd(&sums[hc0 + r], s[r]);
                atomicAdd(&sums[HDIM + hc0 + r], s2[r]);
            }
        }
    }
}

// ---------------------------------------------------------------------------
__global__ __launch_bounds__(256) void final_kernel(
    const float* __restrict__ x, const float* __restrict__ sums,
    const float* __restrict__ gamma, const float* __restrict__ beta,
    float* __restrict__ out)
{
    const int i4 = blockIdx.x * 256 + threadIdx.x;   // float4 index
    const int j  = (i4 & 63) * 4;
    f32x4 mean = *(const f32x4*)(sums + j) * (1.0f / N_NODES);
    f32x4 s2   = *(const f32x4*)(sums + HDIM + j) * (1.0f / N_NODES);
    f32x4 g    = *(const f32x4*)(gamma + j);
    f32x4 b    = *(const f32x4*)(beta + j);
    f32x4 hv   = ((f32x4*)out)[i4];
    f32x4 xv   = ((const f32x4*)x)[i4];
    f32x4 var  = s2 - mean * mean;
    f32x4 inv;
    #pragma unroll
    for (int r = 0; r < 4; ++r) inv[r] = rsqrtf(var[r] + BN_EPS);
    ((f32x4*)out)[i4] = xv + g * (hv - mean) * inv + b;
}

extern "C" void kernel_launch(void* const* d_in, const int* in_sizes, int n_in,
                              void* d_out, int out_size, void* d_ws, size_t ws_size,
                              hipStream_t stream) {
    const float* x     = (const float*)d_in[0];
    const float* rbf   = (const float*)d_in[1];
    const int*   ei    = (const int*)d_in[2];
    const float* Wf1   = (const float*)d_in[3];
    const float* bf1   = (const float*)d_in[4];
    const float* Wf2   = (const float*)d_in[5];
    const float* bf2   = (const float*)d_in[6];
    const float* Wu1   = (const float*)d_in[7];
    const float* bu1   = (const float*)d_in[8];
    const float* Wu2   = (const float*)d_in[9];
    const float* bu2   = (const float*)d_in[10];
    const float* gamma = (const float*)d_in[11];
    const float* beta  = (const float*)d_in[12];
    float* out = (float*)d_out;

    char* ws = (char*)d_ws;
    float* agg     = (float*)(ws);                            // 10,240,000 B
    float* sums    = (float*)(ws + 10240000);                 // 2,048 B
    int*   cnt     = (int*)(ws + 10242048);                   // 40,960 B
    int*   perm    = (int*)(ws + 10283008);                   // 1,280,000 B
    int*   nodepos = (int*)(ws + 11563008);                   // 1,280,000 B
    unsigned short* Pf2 = (unsigned short*)(ws + 12843008);   // 131,072 B
    unsigned short* Pu1 = (unsigned short*)(ws + 12974080);   // 131,072 B
    unsigned short* Pu2 = (unsigned short*)(ws + 13105152);   // 131,072 B
    unsigned short* P1  = (unsigned short*)(ws + 13236224);   // 16,384 B

    // one memset covers agg + sums + cnt (contiguous)
    hipMemsetAsync(agg, 0, 10283008, stream);

    prep_hist_kernel<<<2050, 256, 0, stream>>>(Wf2, Wu1, Wu2, Wf1, bf1, ei,
                                               Pf2, Pu1, Pu2, P1, cnt);
    scan_kernel<<<1, 256, 0, stream>>>(cnt);
    fill_kernel<<<E_EDGES / 256, 256, 0, stream>>>(ei, cnt, perm, nodepos);

    edge_kernel<<<E_EDGES / 64, 256, 0, stream>>>(
        rbf, ei + E_EDGES, perm, nodepos, P1, Pf2, bf2, x, agg);
    node_kernel<<<(N_NODES + 63) / 64, 256, 0, stream>>>(
        agg, bu1, bu2, Pu1, Pu2, out, sums);
    final_kernel<<<(N_NODES * HDIM / 4) / 256, 256, 0, stream>>>(
        x, sums, gamma, beta, out);
}

// Round 9
// 196.458 us; speedup vs baseline: 1.5640x; 1.0268x over previous
//
#include <hip/hip_runtime.h>

#define N_NODES 10000
#define E_EDGES 320000
#define HDIM    256
#define NG      20
#define BN_EPS  1e-5f

typedef __attribute__((ext_vector_type(8))) short short8;
typedef __attribute__((ext_vector_type(4))) float f32x4;

__device__ __forceinline__ float silu_f(float v) {
    float e = __expf(-v);
    return v * __builtin_amdgcn_rcpf(1.0f + e);
}

__device__ __forceinline__ unsigned int cvt_pk(float lo, float hi) {
    unsigned int r;
    asm("v_cvt_pk_bf16_f32 %0, %1, %2" : "=v"(r) : "v"(lo), "v"(hi));
    return r;
}

__device__ __forceinline__ unsigned short f2bf(float f) {
    union { float f; unsigned int u; } v; v.f = f;
    unsigned int r = v.u + 0x7fffu + ((v.u >> 16) & 1u);   // RNE
    return (unsigned short)(r >> 16);
}

__device__ __forceinline__ f32x4 bf4_to_f32(uint2 u) {
    union { unsigned int i; float f; } a, b, c, d;
    a.i = u.x << 16; b.i = u.x & 0xFFFF0000u;
    c.i = u.y << 16; d.i = u.y & 0xFFFF0000u;
    return (f32x4){a.f, b.f, c.f, d.f};
}

// ---------------------------------------------------------------------------
// Fused prep: weight packing + edge histogram + x -> bf16 cast.
// blocks [0,800): pack Pf2/Pu1/Pu2 (3x65536) + P1 (8192)
// blocks [800,2050): histogram of ei_row into cnt
// blocks [2050,3300): xb = bf16(x)   (8 floats/thread)
// ---------------------------------------------------------------------------
__global__ __launch_bounds__(256) void prep_hist_kernel(
    const float* __restrict__ Wf2, const float* __restrict__ Wu1,
    const float* __restrict__ Wu2, const float* __restrict__ Wf1,
    const float* __restrict__ bf1, const int* __restrict__ ei_row,
    const float* __restrict__ x,
    unsigned short* __restrict__ Pf2, unsigned short* __restrict__ Pu1,
    unsigned short* __restrict__ Pu2, unsigned short* __restrict__ P1,
    int* __restrict__ cnt, unsigned short* __restrict__ xb)
{
    const int bx = blockIdx.x;
    if (bx >= 2050) {
        const int idx = ((bx - 2050) * 256 + threadIdx.x) * 8;
        const float4* s = (const float4*)(x + idx);
        float4 a = s[0], b = s[1];
        *(uint4*)(xb + idx) = make_uint4(cvt_pk(a.x, a.y), cvt_pk(a.z, a.w),
                                         cvt_pk(b.x, b.y), cvt_pk(b.z, b.w));
        return;
    }
    if (bx >= 800) {
        int e = (bx - 800) * 256 + threadIdx.x;
        atomicAdd(&cnt[ei_row[e]], 1);
        return;
    }
    int tid = bx * 256 + threadIdx.x;
    if (tid < 196608) {
        int which = tid >> 16, local = tid & 65535;
        const float* W = (which == 0) ? Wf2 : (which == 1) ? Wu1 : Wu2;
        unsigned short* P = (which == 0) ? Pf2 : (which == 1) ? Pu1 : Pu2;
        int j = local & 7, lane = (local >> 3) & 63;
        int ntile = (local >> 9) & 15, kstep = local >> 13;
        int k = kstep * 32 + (lane >> 4) * 8 + j;
        int n = ntile * 16 + (lane & 15);
        P[local] = f2bf(W[k * 256 + n]);
    } else {
        int local = tid - 196608;   // 0..8191
        int j = local & 7, lane = (local >> 3) & 63, ntile = local >> 9;
        int k = (lane >> 4) * 8 + j;
        int n = ntile * 16 + (lane & 15);
        float v = (k < NG) ? Wf1[k * 256 + n] : (k == NG ? bf1[n] : 0.0f);
        P1[local] = f2bf(v);
    }
}

// ---------------------------------------------------------------------------
// CSR build: scan + fill
// ---------------------------------------------------------------------------
__global__ __launch_bounds__(256) void scan_kernel(int* __restrict__ cnt) {
    __shared__ int tot[256];
    const int t = threadIdx.x;
    int loc[40];
    int s = 0;
    #pragma unroll
    for (int i = 0; i < 40; ++i) { loc[i] = cnt[t * 40 + i]; s += loc[i]; }
    tot[t] = s;
    __syncthreads();
    for (int off = 1; off < 256; off <<= 1) {
        int u = (t >= off) ? tot[t - off] : 0;
        __syncthreads();
        tot[t] += u;
        __syncthreads();
    }
    int pre = tot[t] - s;
    #pragma unroll
    for (int i = 0; i < 40; ++i) { int v = loc[i]; cnt[t * 40 + i] = pre; pre += v; }
}

__global__ __launch_bounds__(256) void fill_kernel(const int* __restrict__ ei_row,
                                                   int* __restrict__ cnt,
                                                   int* __restrict__ perm,
                                                   int* __restrict__ nodepos) {
    int e = blockIdx.x * 256 + threadIdx.x;
    int r = ei_row[e];
    int pos = atomicAdd(&cnt[r], 1);
    perm[pos] = e;
    nodepos[pos] = r;
}

// ---------------------------------------------------------------------------
// Edge kernel: 64 CSR-ordered edges / block, 4 waves, 4 blocks/CU.
// GEMM1 (swapped): hiddenT = Wf1T.rbfT; rbf staged once in LDS (80B rows).
// GEMM2 (swapped): filtT = Wf2T.hiddenT; A-frags streamed from L2 packed W.
// msg = (filt+bf2)*xb[col] (bf16 x gather: half the bytes, ~L2-resident)
//   -> f32 LDS overlay (2 passes), serial segmented column reduce,
//   contiguous per-node-row atomics into agg.
// ---------------------------------------------------------------------------
#define SM_NID 0        // 64 int
#define SM_COL 256      // 64 int
#define SM_RBF 512      // [64][40] ushort rows of 80 B (5120 B)
#define SM_HID 5632     // 32768 B: hid bf16 [64][256] swz / msg f32 [32][256] swz
#define SM_TOT 38400

__global__ __launch_bounds__(256, 4) void edge_kernel(
    const float* __restrict__ rbf, const int* __restrict__ ei_col,
    const int* __restrict__ perm, const int* __restrict__ nodepos,
    const unsigned short* __restrict__ P1, const unsigned short* __restrict__ P2,
    const float* __restrict__ bf2, const unsigned short* __restrict__ xb,
    float* __restrict__ agg)
{
    __shared__ char sm[SM_TOT];
    int* nid_s = (int*)(sm + SM_NID);
    int* col_s = (int*)(sm + SM_COL);

    const int t = threadIdx.x;
    int blk = blockIdx.x;
    blk = (blk & 7) * 625 + (blk >> 3);   // XCD swizzle (5000 = 8*625, bijective)
    const int p0 = blk * 64;
    const int l = t & 63, w = t >> 6;
    const int l15 = l & 15, l4 = l >> 4;

    if (t < 64) {
        nid_s[t] = nodepos[p0 + t];
        col_s[t] = ei_col[perm[p0 + t]];
    }
    // rbf -> LDS bf16, 80 B rows; k=20 bias row (1.0), 21..31 zero
    if (t < 128) {
        const int row = t >> 1, half = t & 1;
        const float* rp = rbf + (size_t)perm[p0 + row] * NG + half * 10;
        float v[10];
        if (half == 0) {
            float4 a = *(const float4*)rp, b = *(const float4*)(rp + 4);
            float2 c = *(const float2*)(rp + 8);
            v[0]=a.x; v[1]=a.y; v[2]=a.z; v[3]=a.w; v[4]=b.x;
            v[5]=b.y; v[6]=b.z; v[7]=b.w; v[8]=c.x; v[9]=c.y;
        } else {
            float2 a = *(const float2*)rp;
            float4 b = *(const float4*)(rp + 2), c = *(const float4*)(rp + 6);
            v[0]=a.x; v[1]=a.y; v[2]=b.x; v[3]=b.y; v[4]=b.z;
            v[5]=b.w; v[6]=c.x; v[7]=c.y; v[8]=c.z; v[9]=c.w;
        }
        unsigned int* dst = (unsigned int*)(sm + SM_RBF + row * 80 + half * 20);
        #pragma unroll
        for (int i = 0; i < 5; ++i) dst[i] = cvt_pk(v[2*i], v[2*i+1]);
    } else if (t < 192) {
        const int row = t - 128;
        *(unsigned long long*)(sm + SM_RBF + row * 80 + 40) = 0x3F80ull; // 1.0,0,0,0
        *(uint4*)(sm + SM_RBF + row * 80 + 48) = make_uint4(0, 0, 0, 0);
    }

    // GEMM1 A-frags (Wf1T) and GEMM2 ks=0 A-frags (Wf2T) from global
    short8 a1[4], acur[4];
    #pragma unroll
    for (int mt = 0; mt < 4; ++mt) {
        a1[mt]   = *(const short8*)(P1 + ((4 * w + mt) * 64 + l) * 8);
        acur[mt] = *(const short8*)(P2 + ((4 * w + mt) * 64 + l) * 8);
    }

    __syncthreads();

    f32x4 acc[4][4];   // [mt][nt]
    #pragma unroll
    for (int mt = 0; mt < 4; ++mt)
        #pragma unroll
        for (int nt = 0; nt < 4; ++nt) acc[mt][nt] = (f32x4)0.0f;

    // GEMM1: one K=32 step; B = rbfT from LDS (stride 80B)
    #pragma unroll
    for (int nt = 0; nt < 4; ++nt) {
        short8 bfr = *(const short8*)(sm + SM_RBF + (nt * 16 + l15) * 80 + l4 * 16);
        #pragma unroll
        for (int mt = 0; mt < 4; ++mt)
            acc[mt][nt] = __builtin_amdgcn_mfma_f32_16x16x32_bf16(a1[mt], bfr, acc[mt][nt], 0, 0, 0);
    }

    // silu -> hid bf16, XOR-swizzled, b64 stores
    #pragma unroll
    for (int mt = 0; mt < 4; ++mt) {
        const int hc0 = w * 64 + mt * 16 + l4 * 4;
        #pragma unroll
        for (int nt = 0; nt < 4; ++nt) {
            const int row = nt * 16 + l15;
            unsigned int pk0 = cvt_pk(silu_f(acc[mt][nt][0]), silu_f(acc[mt][nt][1]));
            unsigned int pk1 = cvt_pk(silu_f(acc[mt][nt][2]), silu_f(acc[mt][nt][3]));
            *(uint2*)(sm + SM_HID + row * 512 +
                      (((hc0 >> 3) ^ (row & 7)) << 4) + (hc0 & 7) * 2) =
                make_uint2(pk0, pk1);
        }
    }
    __syncthreads();

    // GEMM2: filtT = Wf2T.hiddenT
    #pragma unroll
    for (int mt = 0; mt < 4; ++mt)
        #pragma unroll
        for (int nt = 0; nt < 4; ++nt) acc[mt][nt] = (f32x4)0.0f;

    for (int ks = 0; ks < 8; ++ks) {
        short8 anext[4];
        if (ks < 7) {
            #pragma unroll
            for (int mt = 0; mt < 4; ++mt)
                anext[mt] = *(const short8*)(P2 + (((ks + 1) * 16 + 4 * w + mt) * 64 + l) * 8);
        }
        #pragma unroll
        for (int nt = 0; nt < 4; ++nt) {
            const int row = nt * 16 + l15;
            short8 bfh = *(const short8*)(sm + SM_HID + row * 512 +
                            ((((ks << 2) + l4) ^ (row & 7)) << 4));
            #pragma unroll
            for (int mt = 0; mt < 4; ++mt)
                acc[mt][nt] = __builtin_amdgcn_mfma_f32_16x16x32_bf16(acur[mt], bfh, acc[mt][nt], 0, 0, 0);
        }
        if (ks < 7) {
            #pragma unroll
            for (int mt = 0; mt < 4; ++mt) acur[mt] = anext[mt];
        }
    }
    __syncthreads();   // all hid reads done -> msg overlay

    f32x4 bc4[4];
    #pragma unroll
    for (int mt = 0; mt < 4; ++mt)
        bc4[mt] = *(const f32x4*)(bf2 + w * 64 + mt * 16 + l4 * 4);

    const unsigned short* xbase[4];
    #pragma unroll
    for (int nt = 0; nt < 4; ++nt)
        xbase[nt] = xb + (size_t)col_s[nt * 16 + l15] * HDIM;

    float sum = 0.0f;
    int cur = nid_s[0];

    // ---- pass 0: edge rows 0..31 (bf16 x loaded inline) ----
    {
        uint2 xp[8];
        #pragma unroll
        for (int mt = 0; mt < 4; ++mt) {
            const int fc0 = w * 64 + mt * 16 + l4 * 4;
            xp[mt]     = *(const uint2*)(xbase[0] + fc0);
            xp[4 + mt] = *(const uint2*)(xbase[1] + fc0);
        }
        #pragma unroll
        for (int ni = 0; ni < 2; ++ni) {
            const int pos = ni * 16 + l15;
            #pragma unroll
            for (int mt = 0; mt < 4; ++mt) {
                const int fc0 = w * 64 + mt * 16 + l4 * 4;
                f32x4 mv = (acc[mt][ni] + bc4[mt]) * bf4_to_f32(xp[ni * 4 + mt]);
                *(f32x4*)(sm + SM_HID + pos * 1024 + (((fc0 >> 2) ^ (pos & 7)) << 4)) = mv;
            }
        }
    }
    // prefetch bf16 x for pass 1 (latency hidden under reduce pass 0)
    uint2 xq[8];
    #pragma unroll
    for (int mt = 0; mt < 4; ++mt) {
        const int fc0 = w * 64 + mt * 16 + l4 * 4;
        xq[mt]     = *(const uint2*)(xbase[2] + fc0);
        xq[4 + mt] = *(const uint2*)(xbase[3] + fc0);
    }
    __syncthreads();
    for (int pos = 0; pos < 32; ++pos) {
        const int nid = nid_s[pos];
        float v = *(const float*)(sm + SM_HID + pos * 1024 +
                    (((t >> 2) ^ (pos & 7)) << 4) + (t & 3) * 4);
        if (nid != cur) {
            atomicAdd(&agg[(size_t)cur * HDIM + t], sum);
            sum = 0.0f; cur = nid;
        }
        sum += v;
    }
    __syncthreads();

    // ---- pass 1: edge rows 32..63 ----
    #pragma unroll
    for (int ni = 0; ni < 2; ++ni) {
        const int nt  = 2 + ni;
        const int pos = ni * 16 + l15;
        #pragma unroll
        for (int mt = 0; mt < 4; ++mt) {
            const int fc0 = w * 64 + mt * 16 + l4 * 4;
            f32x4 mv = (acc[mt][nt] + bc4[mt]) * bf4_to_f32(xq[ni * 4 + mt]);
            *(f32x4*)(sm + SM_HID + pos * 1024 + (((fc0 >> 2) ^ (pos & 7)) << 4)) = mv;
        }
    }
    __syncthreads();
    for (int pos = 0; pos < 32; ++pos) {
        const int nid = nid_s[32 + pos];
        float v = *(const float*)(sm + SM_HID + pos * 1024 +
                    (((t >> 2) ^ (pos & 7)) << 4) + (t & 3) * 4);
        if (nid != cur) {
            atomicAdd(&agg[(size_t)cur * HDIM + t], sum);
            sum = 0.0f; cur = nid;
        }
        sum += v;
    }
    atomicAdd(&agg[(size_t)cur * HDIM + t], sum);
}

// ---------------------------------------------------------------------------
// Node kernel (round-4 structure): 64 rows/block, both GEMMs swapped,
// fused BN partials. LDS 32KB.
// ---------------------------------------------------------------------------
__global__ __launch_bounds__(256, 3) void node_kernel(
    const float* __restrict__ agg, const float* __restrict__ bu1,
    const float* __restrict__ bu2,
    const unsigned short* __restrict__ Pu1, const unsigned short* __restrict__ Pu2,
    float* __restrict__ hout, float* __restrict__ sums)
{
    __shared__ char sm[32768];    // [64 nodes][256] bf16, XOR-swizzled
    const int t  = threadIdx.x;
    const int r0 = blockIdx.x * 64;
    const int l = t & 63, w = t >> 6;
    const int l15 = l & 15, l4 = l >> 4;

    // stage agg -> LDS bf16 (float4 + cvt_pk + b64)
    {
        const int row = t & 63, q = t >> 6;
        const bool valid = (r0 + row) < N_NODES;
        const float4* src = (const float4*)(agg + (size_t)(r0 + row) * HDIM) + q * 16;
        #pragma unroll
        for (int i = 0; i < 16; ++i) {
            float4 v = valid ? src[i] : make_float4(0.f, 0.f, 0.f, 0.f);
            const int c0 = q * 64 + i * 4;
            *(uint2*)(sm + row * 512 + (((c0 >> 3) ^ (row & 7)) << 4) + (c0 & 7) * 2) =
                make_uint2(cvt_pk(v.x, v.y), cvt_pk(v.z, v.w));
        }
    }

    short8 acur[4];
    #pragma unroll
    for (int mt = 0; mt < 4; ++mt)
        acur[mt] = *(const short8*)(Pu1 + ((4 * w + mt) * 64 + l) * 8);

    __syncthreads();

    f32x4 acc[4][4];
    #pragma unroll
    for (int mt = 0; mt < 4; ++mt)
        #pragma unroll
        for (int nt = 0; nt < 4; ++nt) acc[mt][nt] = (f32x4)0.0f;

    // GEMM1': midT = Wu1T.aggT
    for (int ks = 0; ks < 8; ++ks) {
        short8 anext[4];
        if (ks < 7) {
            #pragma unroll
            for (int mt = 0; mt < 4; ++mt)
                anext[mt] = *(const short8*)(Pu1 + (((ks + 1) * 16 + 4 * w + mt) * 64 + l) * 8);
        }
        #pragma unroll
        for (int nt = 0; nt < 4; ++nt) {
            const int row = nt * 16 + l15;
            short8 bfa = *(const short8*)(sm + row * 512 +
                            ((((ks << 2) + l4) ^ (row & 7)) << 4));
            #pragma unroll
            for (int mt = 0; mt < 4; ++mt)
                acc[mt][nt] = __builtin_amdgcn_mfma_f32_16x16x32_bf16(acur[mt], bfa, acc[mt][nt], 0, 0, 0);
        }
        if (ks < 7) {
            #pragma unroll
            for (int mt = 0; mt < 4; ++mt) acur[mt] = anext[mt];
        }
    }
    __syncthreads();   // all reads done; overwrite with mid

    #pragma unroll
    for (int mt = 0; mt < 4; ++mt)
        acur[mt] = *(const short8*)(Pu2 + ((4 * w + mt) * 64 + l) * 8);

    // mid = silu(acc + bu1) -> LDS (b64 stores)
    #pragma unroll
    for (int mt = 0; mt < 4; ++mt) {
        const int mc0 = w * 64 + mt * 16 + l4 * 4;
        f32x4 b4 = *(const f32x4*)(bu1 + mc0);
        #pragma unroll
        for (int nt = 0; nt < 4; ++nt) {
            const int row = nt * 16 + l15;
            unsigned int pk0 = cvt_pk(silu_f(acc[mt][nt][0] + b4[0]), silu_f(acc[mt][nt][1] + b4[1]));
            unsigned int pk1 = cvt_pk(silu_f(acc[mt][nt][2] + b4[2]), silu_f(acc[mt][nt][3] + b4[3]));
            *(uint2*)(sm + row * 512 + (((mc0 >> 3) ^ (row & 7)) << 4) + (mc0 & 7) * 2) =
                make_uint2(pk0, pk1);
            acc[mt][nt] = (f32x4)0.0f;
        }
    }
    __syncthreads();

    // GEMM2': hT = Wu2T.midT
    for (int ks = 0; ks < 8; ++ks) {
        short8 anext[4];
        if (ks < 7) {
            #pragma unroll
            for (int mt = 0; mt < 4; ++mt)
                anext[mt] = *(const short8*)(Pu2 + (((ks + 1) * 16 + 4 * w + mt) * 64 + l) * 8);
        }
        #pragma unroll
        for (int nt = 0; nt < 4; ++nt) {
            const int row = nt * 16 + l15;
            short8 bfm = *(const short8*)(sm + row * 512 +
                            ((((ks << 2) + l4) ^ (row & 7)) << 4));
            #pragma unroll
            for (int mt = 0; mt < 4; ++mt)
                acc[mt][nt] = __builtin_amdgcn_mfma_f32_16x16x32_bf16(acur[mt], bfm, acc[mt][nt], 0, 0, 0);
        }
        if (ks < 7) {
            #pragma unroll
            for (int mt = 0; mt < 4; ++mt) acur[mt] = anext[mt];
        }
    }

    // epilogue: float4 h stores + BN partials
    #pragma unroll
    for (int mt = 0; mt < 4; ++mt) {
        const int hc0 = w * 64 + mt * 16 + l4 * 4;
        f32x4 b4 = *(const f32x4*)(bu2 + hc0);
        f32x4 s = (f32x4)0.0f, s2 = (f32x4)0.0f;
        #pragma unroll
        for (int nt = 0; nt < 4; ++nt) {
            const int gr = r0 + nt * 16 + l15;
            if (gr < N_NODES) {
                f32x4 hv = acc[mt][nt] + b4;
                *(f32x4*)(hout + (size_t)gr * HDIM + hc0) = hv;
                s += hv; s2 += hv * hv;
            }
        }
        #pragma unroll
        for (int off = 1; off < 16; off <<= 1) {
            #pragma unroll
            for (int r = 0; r < 4; ++r) {
                s[r]  += __shfl_xor(s[r], off);
                s2[r] += __shfl_xor(s2[r], off);
            }
        }
        if (l15 == 0) {
            #pragma unroll
            for (int r = 0; r < 4; ++r) {
                atomicAdd(&sums[hc0 + r], s[r]);
                atomicAdd(&sums[HDIM + hc0 + r], s2[r]);
            }
        }
    }
}

// ---------------------------------------------------------------------------
__global__ __launch_bounds__(256) void final_kernel(
    const float* __restrict__ x, const float* __restrict__ sums,
    const float* __restrict__ gamma, const float* __restrict__ beta,
    float* __restrict__ out)
{
    const int i4 = blockIdx.x * 256 + threadIdx.x;   // float4 index
    const int j  = (i4 & 63) * 4;
    f32x4 mean = *(const f32x4*)(sums + j) * (1.0f / N_NODES);
    f32x4 s2   = *(const f32x4*)(sums + HDIM + j) * (1.0f / N_NODES);
    f32x4 g    = *(const f32x4*)(gamma + j);
    f32x4 b    = *(const f32x4*)(beta + j);
    f32x4 hv   = ((f32x4*)out)[i4];
    f32x4 xv   = ((const f32x4*)x)[i4];
    f32x4 var  = s2 - mean * mean;
    f32x4 inv;
    #pragma unroll
    for (int r = 0; r < 4; ++r) inv[r] = rsqrtf(var[r] + BN_EPS);
    ((f32x4*)out)[i4] = xv + g * (hv - mean) * inv + b;
}

extern "C" void kernel_launch(void* const* d_in, const int* in_sizes, int n_in,
                              void* d_out, int out_size, void* d_ws, size_t ws_size,
                              hipStream_t stream) {
    const float* x     = (const float*)d_in[0];
    const float* rbf   = (const float*)d_in[1];
    const int*   ei    = (const int*)d_in[2];
    const float* Wf1   = (const float*)d_in[3];
    const float* bf1   = (const float*)d_in[4];
    const float* Wf2   = (const float*)d_in[5];
    const float* bf2   = (const float*)d_in[6];
    const float* Wu1   = (const float*)d_in[7];
    const float* bu1   = (const float*)d_in[8];
    const float* Wu2   = (const float*)d_in[9];
    const float* bu2   = (const float*)d_in[10];
    const float* gamma = (const float*)d_in[11];
    const float* beta  = (const float*)d_in[12];
    float* out = (float*)d_out;

    char* ws = (char*)d_ws;
    float* agg     = (float*)(ws);                            // 10,240,000 B
    float* sums    = (float*)(ws + 10240000);                 // 2,048 B
    int*   cnt     = (int*)(ws + 10242048);                   // 40,960 B
    int*   perm    = (int*)(ws + 10283008);                   // 1,280,000 B
    int*   nodepos = (int*)(ws + 11563008);                   // 1,280,000 B
    unsigned short* Pf2 = (unsigned short*)(ws + 12843008);   // 131,072 B
    unsigned short* Pu1 = (unsigned short*)(ws + 12974080);   // 131,072 B
    unsigned short* Pu2 = (unsigned short*)(ws + 13105152);   // 131,072 B
    unsigned short* P1  = (unsigned short*)(ws + 13236224);   // 16,384 B

    // bf16 x lives in d_out's first 5.12 MB: edge reads it, then node_kernel
    // fully overwrites d_out with h (edge completes before node launches).
    unsigned short* xb = (unsigned short*)d_out;

    // one memset covers agg + sums + cnt (contiguous)
    hipMemsetAsync(agg, 0, 10283008, stream);

    prep_hist_kernel<<<3300, 256, 0, stream>>>(Wf2, Wu1, Wu2, Wf1, bf1, ei, x,
                                               Pf2, Pu1, Pu2, P1, cnt, xb);
    scan_kernel<<<1, 256, 0, stream>>>(cnt);
    fill_kernel<<<E_EDGES / 256, 256, 0, stream>>>(ei, cnt, perm, nodepos);

    edge_kernel<<<E_EDGES / 64, 256, 0, stream>>>(
        rbf, ei + E_EDGES, perm, nodepos, P1, Pf2, bf2, xb, agg);
    node_kernel<<<(N_NODES + 63) / 64, 256, 0, stream>>>(
        agg, bu1, bu2, Pu1, Pu2, out, sums);
    final_kernel<<<(N_NODES * HDIM / 4) / 256, 256, 0, stream>>>(
        x, sums, gamma, beta, out);
}